// Round 1
// baseline (355.844 us; speedup 1.0000x reference)
//
#include <hip/hip_runtime.h>
#include <math.h>

// ---------------------------------------------------------------------------
// FusionMoE R3: 2-phase double-buffered prefetch pipeline (T3-minimum) in all
// GEMM kernels. Raw s_barrier + counted vmcnt keeps prefetch loads in flight
// across barriers (HIP __syncthreads would drain vmcnt(0)). combine: x tile
// moved to registers so dbuf fits at 2 blocks/CU; pipeline runs across all
// 16 (expert,kit) stage pairs. Math identical to R2.
// ---------------------------------------------------------------------------

typedef unsigned short u16;
typedef unsigned int u32;
typedef __attribute__((ext_vector_type(8))) short bf16x8;
typedef __attribute__((ext_vector_type(4))) float f32x4;

__device__ __forceinline__ float bf2f(u16 u) {
    union { u32 i; float f; } v; v.i = ((u32)u) << 16; return v.f;
}
__device__ __forceinline__ u16 f2bf(float f) {  // RNE
    union { float f; u32 i; } v; v.f = f;
    u32 x = v.i;
    return (u16)((x + 0x7fffu + ((x >> 16) & 1u)) >> 16);
}
__device__ __forceinline__ float gelu_exact(float v) {
    return 0.5f * v * (1.0f + erff(v * 0.70710678118654752f));
}

typedef __attribute__((address_space(1))) void GV;
typedef __attribute__((address_space(3))) void SV;
__device__ __forceinline__ void gldlds(const void* g, void* l) {
    __builtin_amdgcn_global_load_lds((GV*)g, (SV*)l, 16, 0, 0);
}

// pack two f32 (bit-truncate) into one u32 of two bf16 (f0 low, f1 high)
__device__ __forceinline__ u32 pk2(u32 f0, u32 f1) {
    return __builtin_amdgcn_perm(f1, f0, 0x07060302);
}

// counted-vmcnt wait (keeps newest N loads in flight), memory-clobbered so the
// compiler can't move gldlds/ds ops across it.
#define WAIT_VM(N) asm volatile("s_waitcnt vmcnt(" #N ")" ::: "memory")
// raw barrier with compiler memory fences on both sides (no vmcnt drain)
#define BARRIER()                                    \
    do {                                             \
        asm volatile("" ::: "memory");               \
        __builtin_amdgcn_s_barrier();                \
        asm volatile("" ::: "memory");               \
    } while (0)
// LDS-visibility barrier (lgkmcnt only — leaves prefetch vmcnt in flight)
#define LGKBAR()                                            \
    do {                                                    \
        asm volatile("s_waitcnt lgkmcnt(0)" ::: "memory");  \
        __builtin_amdgcn_s_barrier();                       \
        asm volatile("" ::: "memory");                      \
    } while (0)

// ----- bf16 staging helpers (XOR-8 swizzle), verified in R1 -----
__device__ __forceinline__ void stageA64(const u16* Ag, int lda, u16* As, int tid) {
#pragma unroll
    for (int i = 0; i < 2; ++i) {
        int s = i * 256 + tid;          // 512 slots (64 rows x 8 chunks of 16B)
        int m = s >> 3, c = s & 7;
        gldlds(Ag + m * lda + (c ^ (m & 7)) * 8, As + s * 8);
    }
}
__device__ __forceinline__ void stageA64_R32(const u16* Ag, int lda, u16* As, int tid) {
    int s = tid;                        // 256 slots (32 rows x 8 chunks)
    int m = s >> 3, c = s & 7;
    gldlds(Ag + m * lda + (c ^ (m & 7)) * 8, As + s * 8);
}
__device__ __forceinline__ void stageB64(const u16* Bg, int ldb, u16* Bs, int tid) {
#pragma unroll
    for (int i = 0; i < 8; ++i) {
        int s = i * 256 + tid;          // 2048 slots (256 n-rows x 8 chunks)
        int n = s >> 3, c = s & 7;
        gldlds(Bg + n * ldb + (c ^ (n & 7)) * 8, Bs + s * 8);
    }
}
__device__ __forceinline__ void compute64(const u16* As, const u16* Bs, f32x4 acc[4][4],
                                          int w, int l16, int quad) {
#pragma unroll
    for (int ks = 0; ks < 2; ++ks) {
        bf16x8 a[4];
#pragma unroll
        for (int mt = 0; mt < 4; ++mt) {
            int m = mt * 16 + l16;
            a[mt] = *(const bf16x8*)(As + m * 64 + (((ks * 4 + quad) ^ (m & 7)) << 3));
        }
#pragma unroll
        for (int nt = 0; nt < 4; ++nt) {
            int n = w * 64 + nt * 16 + l16;
            bf16x8 b = *(const bf16x8*)(Bs + n * 64 + (((ks * 4 + quad) ^ (n & 7)) << 3));
#pragma unroll
            for (int mt = 0; mt < 4; ++mt)
                acc[mt][nt] = __builtin_amdgcn_mfma_f32_16x16x32_bf16(a[mt], b, acc[mt][nt], 0, 0, 0);
        }
    }
}
__device__ __forceinline__ void compute64_R32(const u16* As, const u16* Bs, f32x4 acc[2][4],
                                              int w, int l16, int quad) {
#pragma unroll
    for (int ks = 0; ks < 2; ++ks) {
        bf16x8 a[2];
#pragma unroll
        for (int mt = 0; mt < 2; ++mt) {
            int m = mt * 16 + l16;
            a[mt] = *(const bf16x8*)(As + m * 64 + (((ks * 4 + quad) ^ (m & 7)) << 3));
        }
#pragma unroll
        for (int nt = 0; nt < 4; ++nt) {
            int n = w * 64 + nt * 16 + l16;
            bf16x8 b = *(const bf16x8*)(Bs + n * 64 + (((ks * 4 + quad) ^ (n & 7)) << 3));
#pragma unroll
            for (int mt = 0; mt < 2; ++mt)
                acc[mt][nt] = __builtin_amdgcn_mfma_f32_16x16x32_bf16(a[mt], b, acc[mt][nt], 0, 0, 0);
        }
    }
}

// ---------------------------------------------------------------------------
// K0: prep — weight transposes to bf16 + lbacc zero (weights only, ~7 MB)
// ---------------------------------------------------------------------------
#define SEG_WF  409600
#define SEG_W1  524288
#define SEG_W2  524288
#define SEG_W3  262144
#define PREP_ITEMS (SEG_WF + SEG_W1 + SEG_W2 + SEG_W3 + 8)

__global__ __launch_bounds__(256) void prep_kernel(
    const float* __restrict__ Wf, const float* __restrict__ W1, const float* __restrict__ W2,
    const float* __restrict__ W3,
    u16* __restrict__ wft, u16* __restrict__ w1t, u16* __restrict__ w2t, u16* __restrict__ w3t,
    float* __restrict__ lbacc) {
    int idx = blockIdx.x * 256 + threadIdx.x;
    if (idx < SEG_WF) {  // WfT[n<256][k<1600] = Wf[k][n]
        int n = idx / 1600, k = idx % 1600;
        wft[idx] = f2bf(Wf[(size_t)k * 256 + n]);
        return;
    }
    idx -= SEG_WF;
    if (idx < SEG_W1) {  // W1T[e][n<512][k<256] = W1[e][k][n]
        int e = idx >> 17, r = idx & 131071;
        int n = r >> 8, k = r & 255;
        w1t[idx] = f2bf(W1[(size_t)e * 131072 + (size_t)k * 512 + n]);
        return;
    }
    idx -= SEG_W1;
    if (idx < SEG_W2) {  // W2T[e][n<256][k<512] = W2[e][k][n]
        int e = idx >> 17, r = idx & 131071;
        int n = r >> 9, k = r & 511;
        w2t[idx] = f2bf(W2[(size_t)e * 131072 + (size_t)k * 256 + n]);
        return;
    }
    idx -= SEG_W2;
    if (idx < SEG_W3) {  // W3T[e][n<256][k<256] = W3[e][k][n]
        int e = idx >> 16, r = idx & 65535;
        int n = r >> 8, k = r & 255;
        w3t[idx] = f2bf(W3[(size_t)e * 65536 + (size_t)k * 256 + n]);
        return;
    }
    idx -= SEG_W3;
    if (idx < 8) lbacc[idx] = 0.0f;
}

// ---------------------------------------------------------------------------
// K1: fusion — fp32 A direct, bf16 B, 32x256 tile, 2-phase prefetch pipeline.
// Epilogue: bias+LN+GELU -> xbf, fused gate (fp32 logits) -> wr + lb atomics
// ---------------------------------------------------------------------------
__global__ __launch_bounds__(256) void fusion_kernel(
    const float* __restrict__ vis, const float* __restrict__ lang, const float* __restrict__ state,
    const u16* __restrict__ BT, const float* __restrict__ bfv_, const float* __restrict__ gf,
    const float* __restrict__ bfln, const float* __restrict__ Wg,
    u16* __restrict__ xbf, float* __restrict__ wr, float* __restrict__ lbacc) {
    __shared__ __align__(16) u32 Af[2][2048];   // 2x 8KB: 32 rows x 16 f32-chunks (XOR-16)
    __shared__ __align__(16) u16 Bs[2][16384];  // 2x 32KB: 256 n x 64 k bf16
    int tid = threadIdx.x;
    int w = tid >> 6, lane = tid & 63, quad = lane >> 4, l16 = lane & 15;
    int m0 = blockIdx.x * 32;
    f32x4 acc[2][4] = {};

    auto stage = [&](int b, int kit) {
        const float* base; int ld;
        if (kit < 12)      { base = vis   + (size_t)m0 * 768 + kit * 64;        ld = 768; }
        else if (kit < 24) { base = lang  + (size_t)m0 * 768 + (kit - 12) * 64; ld = 768; }
        else               { base = state + (size_t)m0 * 64;                    ld = 64; }
#pragma unroll
        for (int i = 0; i < 2; ++i) {        // A: 512 slots of 16B (4 f32)
            int s = i * 256 + tid;
            int m = s >> 4, c = s & 15;
            gldlds(base + m * ld + (c ^ (m & 15)) * 4, &Af[b][s * 4]);
        }
        stageB64(BT + kit * 64, 1600, Bs[b], tid);  // 8 loads
    };

    stage(0, 0);                              // prologue: 10 loads in flight
    for (int kit = 0; kit < 25; ++kit) {
        int cur = kit & 1;
        if (kit + 1 < 25) { stage(cur ^ 1, kit + 1); WAIT_VM(10); }  // cur buf ready
        else              { WAIT_VM(0); }
        BARRIER();                            // all waves' cur staging visible
#pragma unroll
        for (int ks = 0; ks < 2; ++ks) {
            bf16x8 a[2];
#pragma unroll
            for (int mt = 0; mt < 2; ++mt) {
                int m = mt * 16 + l16;
                int c0 = ks * 8 + quad * 2;
                const u32* rowp = &Af[cur][m * 64];
                uint4 f0 = *(const uint4*)(rowp + (c0 ^ (m & 15)) * 4);
                uint4 f1 = *(const uint4*)(rowp + ((c0 + 1) ^ (m & 15)) * 4);
                union { u32 u[4]; bf16x8 v; } pk;
                pk.u[0] = pk2(f0.x, f0.y); pk.u[1] = pk2(f0.z, f0.w);
                pk.u[2] = pk2(f1.x, f1.y); pk.u[3] = pk2(f1.z, f1.w);
                a[mt] = pk.v;
            }
#pragma unroll
            for (int nt = 0; nt < 4; ++nt) {
                int n = w * 64 + nt * 16 + l16;
                bf16x8 b = *(const bf16x8*)(Bs[cur] + n * 64 + (((ks * 4 + quad) ^ (n & 7)) << 3));
#pragma unroll
                for (int mt = 0; mt < 2; ++mt)
                    acc[mt][nt] = __builtin_amdgcn_mfma_f32_16x16x32_bf16(a[mt], b, acc[mt][nt], 0, 0, 0);
            }
        }
        BARRIER();                            // reads of cur done -> re-stageable
    }

    // ---- epilogue: bias, LN, GELU, xbf store, fused gate ----
    u32* Af0 = &Af[0][0];
    float2* red  = (float2*)Af0;           // 128 float2 (w*32+rl)
    float*  muv  = (float*)(Af0 + 256);    // 32
    float*  rsv  = (float*)(Af0 + 288);    // 32
    float*  gred = (float*)(Af0 + 512);    // 512: [w][rl][e]
    float*  sacc = (float*)(Af0 + 1024);   // 8

    float bv[4], gvv[4], blv[4]; float4 wgv[4];
#pragma unroll
    for (int nt = 0; nt < 4; ++nt) {
        int col = w * 64 + nt * 16 + l16;
        bv[nt] = bfv_[col]; gvv[nt] = gf[col]; blv[nt] = bfln[col];
        wgv[nt] = *(const float4*)(Wg + col * 4);
    }
    if (tid < 8) sacc[tid] = 0.f;
#pragma unroll
    for (int mt = 0; mt < 2; ++mt)
#pragma unroll
        for (int r = 0; r < 4; ++r) {
            float ss = 0.f, qq = 0.f;
#pragma unroll
            for (int nt = 0; nt < 4; ++nt) {
                float v = acc[mt][nt][r] + bv[nt];
                acc[mt][nt][r] = v;
                ss += v; qq += v * v;
            }
#pragma unroll
            for (int d = 1; d < 16; d <<= 1) { ss += __shfl_xor(ss, d); qq += __shfl_xor(qq, d); }
            if (l16 == 0) red[w * 32 + mt * 16 + quad * 4 + r] = make_float2(ss, qq);
        }
    __syncthreads();
    if (tid < 32) {
        float ss = 0.f, qq = 0.f;
#pragma unroll
        for (int ww = 0; ww < 4; ++ww) { float2 t = red[ww * 32 + tid]; ss += t.x; qq += t.y; }
        float mu = ss * (1.f / 256.f);
        float var = qq * (1.f / 256.f) - mu * mu;
        muv[tid] = mu;
        rsv[tid] = 1.f / sqrtf(var + 1e-5f);
    }
    __syncthreads();
#pragma unroll
    for (int mt = 0; mt < 2; ++mt)
#pragma unroll
        for (int r = 0; r < 4; ++r) {
            int rl = mt * 16 + quad * 4 + r;
            float mu = muv[rl], rs = rsv[rl];
#pragma unroll
            for (int nt = 0; nt < 4; ++nt) {
                int col = w * 64 + nt * 16 + l16;
                float t = (acc[mt][nt][r] - mu) * rs * gvv[nt] + blv[nt];
                float g = gelu_exact(t);
                acc[mt][nt][r] = g;
                xbf[(size_t)(m0 + rl) * 256 + col] = f2bf(g);
            }
        }
    // gate partials (fp32 x, pre-bf16-truncation)
#pragma unroll
    for (int mt = 0; mt < 2; ++mt)
#pragma unroll
        for (int r = 0; r < 4; ++r) {
            int rl = mt * 16 + quad * 4 + r;
            float p0 = 0.f, p1 = 0.f, p2 = 0.f, p3 = 0.f;
#pragma unroll
            for (int nt = 0; nt < 4; ++nt) {
                float g = acc[mt][nt][r];
                p0 += g * wgv[nt].x; p1 += g * wgv[nt].y;
                p2 += g * wgv[nt].z; p3 += g * wgv[nt].w;
            }
#pragma unroll
            for (int d = 1; d < 16; d <<= 1) {
                p0 += __shfl_xor(p0, d); p1 += __shfl_xor(p1, d);
                p2 += __shfl_xor(p2, d); p3 += __shfl_xor(p3, d);
            }
            if (l16 == 0) {
                float* gp = gred + w * 128 + rl * 4;
                gp[0] = p0; gp[1] = p1; gp[2] = p2; gp[3] = p3;
            }
        }
    __syncthreads();
    if (tid < 32) {
        int row = tid;
        float lg[4];
#pragma unroll
        for (int e = 0; e < 4; ++e)
            lg[e] = gred[row * 4 + e] + gred[128 + row * 4 + e] +
                    gred[256 + row * 4 + e] + gred[384 + row * 4 + e];
        float mx = fmaxf(fmaxf(lg[0], lg[1]), fmaxf(lg[2], lg[3]));
        float ex[4]; float Z = 0.f;
#pragma unroll
        for (int e = 0; e < 4; ++e) { ex[e] = expf(lg[e] - mx); Z += ex[e]; }
        int i0 = 0; float v0 = lg[0];
#pragma unroll
        for (int e = 1; e < 4; ++e) if (lg[e] > v0) { v0 = lg[e]; i0 = e; }
        int i1 = -1; float v1 = -1e30f;
#pragma unroll
        for (int e = 0; e < 4; ++e) if (e != i0 && lg[e] > v1) { v1 = lg[e]; i1 = e; }
        float t = expf(v1 - v0);
        float wA = 1.f / (1.f + t), wB = t / (1.f + t);
        float w4[4] = {0.f, 0.f, 0.f, 0.f};
        w4[i0] = wA; w4[i1] = wB;
#pragma unroll
        for (int e = 0; e < 4; ++e) wr[(size_t)(m0 + row) * 4 + e] = w4[e];
#pragma unroll
        for (int e = 0; e < 4; ++e) atomicAdd(&sacc[e], ex[e] / Z);
        atomicAdd(&sacc[4 + i0], 1.f);
        atomicAdd(&sacc[4 + i1], 1.f);
    }
    __syncthreads();
    if (tid < 8) atomicAdd(lbacc + tid, sacc[tid]);
}

// ---------------------------------------------------------------------------
// K2: expert GEMM + bias + GELU, batched over blockIdx.z = expert.
// 2-phase prefetch pipeline (10 loads/iter).
// ---------------------------------------------------------------------------
__global__ __launch_bounds__(256) void expert_gemm_kernel(
    const u16* __restrict__ A, int lda, size_t aE,
    const u16* __restrict__ BT, size_t bE,
    const float* __restrict__ bias, int biasE,
    u16* __restrict__ outp, int ldo, size_t oE) {
    __shared__ __align__(16) u16 As[2][4096];
    __shared__ __align__(16) u16 Bs[2][16384];
    int tid = threadIdx.x;
    int w = tid >> 6, lane = tid & 63, quad = lane >> 4, l16 = lane & 15;
    int m0 = blockIdx.x * 64;
    int col0 = blockIdx.y * 256;
    int e = blockIdx.z;
    f32x4 acc[4][4] = {};
    const u16* Ag = A + e * aE + (size_t)m0 * lda;
    const u16* Bg = BT + e * bE + (size_t)col0 * lda;
    int kiters = lda >> 6;
    stageA64(Ag, lda, As[0], tid);
    stageB64(Bg, lda, Bs[0], tid);
    for (int kit = 0; kit < kiters; ++kit) {
        int cur = kit & 1;
        if (kit + 1 < kiters) {
            stageA64(Ag + (kit + 1) * 64, lda, As[cur ^ 1], tid);
            stageB64(Bg + (kit + 1) * 64, lda, Bs[cur ^ 1], tid);
            WAIT_VM(10);
        } else { WAIT_VM(0); }
        BARRIER();
        compute64(As[cur], Bs[cur], acc, w, l16, quad);
        BARRIER();
    }
#pragma unroll
    for (int nt = 0; nt < 4; ++nt) {
        int col = col0 + w * 64 + nt * 16 + l16;
        float bvv = bias[e * biasE + col];
#pragma unroll
        for (int mt = 0; mt < 4; ++mt)
#pragma unroll
            for (int r = 0; r < 4; ++r) {
                int row = m0 + mt * 16 + quad * 4 + r;
                outp[e * oE + (size_t)row * ldo + col] = f2bf(gelu_exact(acc[mt][nt][r] + bvv));
            }
    }
}

// ---------------------------------------------------------------------------
// K3: combine — 32-row tiles; pipeline across all 16 (e,kit) pairs; x in regs.
// h2@W3 + b3 + x -> LN -> *eg+eb, out += w[row][e]*y; lb by block 0.
// ---------------------------------------------------------------------------
__global__ __launch_bounds__(256) void combine_kernel(
    const u16* __restrict__ h2, const u16* __restrict__ W3T,
    const float* __restrict__ b3, const float* __restrict__ eg, const float* __restrict__ eb,
    const u16* __restrict__ xbf, const float* __restrict__ wr,
    const float* __restrict__ lbacc, float* __restrict__ outp) {
    __shared__ __align__(16) u16 As[2][2048];    // 2x 4KB: 32 rows x 64 k
    __shared__ __align__(16) u16 Bs[2][16384];   // 2x 32KB
    __shared__ float wl[128];
    __shared__ float2 red[128];
    __shared__ float muv[32], rsv[32];
    int tid = threadIdx.x;
    int w = tid >> 6, lane = tid & 63, quad = lane >> 4, l16 = lane & 15;
    int m0 = blockIdx.x * 32;
    if (blockIdx.x == 0 && tid == 0) {           // lb_loss (lbacc complete: fusion done)
        float lb = 0.f;
#pragma unroll
        for (int e = 0; e < 4; ++e)
            lb += (lbacc[4 + e] / 32768.f) * (lbacc[e] / 16384.f);
        outp[4194304] = 4.f * lb;
    }
    // ---- x tile -> registers (bounce through Bs[0], then Bs[0] is reused) ----
    u16* xs = &Bs[0][0];
#pragma unroll
    for (int i = 0; i < 4; ++i) {
        int s = i * 256 + tid;
        *(uint4*)(xs + s * 8) = *(const uint4*)(xbf + (size_t)m0 * 256 + s * 8);
    }
    if (tid < 128) wl[tid] = wr[(size_t)m0 * 4 + tid];
    __syncthreads();
    float xr[2][4][4];
#pragma unroll
    for (int mt = 0; mt < 2; ++mt)
#pragma unroll
        for (int r = 0; r < 4; ++r) {
            int rl = mt * 16 + quad * 4 + r;
#pragma unroll
            for (int nt = 0; nt < 4; ++nt) {
                int col = w * 64 + nt * 16 + l16;
                xr[mt][r][nt] = bf2f(xs[rl * 256 + col]);
            }
        }
    __syncthreads();                             // x reads done; Bs[0] free

    f32x4 oacc[2][4] = {};
    f32x4 acc[2][4] = {};
    auto stage = [&](int b, int p) {             // p = e*4 + kit
        int ee = p >> 2, kit = p & 3;
        stageA64_R32(h2 + ((size_t)ee * 16384 + m0) * 256 + kit * 64, 256, As[b], tid);
        stageB64(W3T + (size_t)ee * 65536 + kit * 64, 256, Bs[b], tid);
    };
    stage(0, 0);                                 // prologue: 9 loads
    for (int p = 0; p < 16; ++p) {
        int cur = p & 1;
        if (p + 1 < 16) { stage(cur ^ 1, p + 1); WAIT_VM(9); }
        else            { WAIT_VM(0); }
        BARRIER();
        compute64_R32(As[cur], Bs[cur], acc, w, l16, quad);
        BARRIER();
        if ((p & 3) == 3) {                      // expert e = p>>2 finished
            int e = p >> 2;
            float b3v[4], egv[4], ebv[4];
#pragma unroll
            for (int nt = 0; nt < 4; ++nt) {
                int col = w * 64 + nt * 16 + l16;
                b3v[nt] = b3[e * 256 + col]; egv[nt] = eg[e * 256 + col]; ebv[nt] = eb[e * 256 + col];
            }
#pragma unroll
            for (int mt = 0; mt < 2; ++mt)
#pragma unroll
                for (int r = 0; r < 4; ++r) {
                    int rl = mt * 16 + quad * 4 + r;
                    float ss = 0.f, qq = 0.f;
#pragma unroll
                    for (int nt = 0; nt < 4; ++nt) {
                        float v = acc[mt][nt][r] + b3v[nt] + xr[mt][r][nt];
                        acc[mt][nt][r] = v;
                        ss += v; qq += v * v;
                    }
#pragma unroll
                    for (int d = 1; d < 16; d <<= 1) { ss += __shfl_xor(ss, d); qq += __shfl_xor(qq, d); }
                    if (l16 == 0) red[w * 32 + rl] = make_float2(ss, qq);
                }
            LGKBAR();                            // keep prefetch vmcnt in flight
            if (tid < 32) {
                float ss = 0.f, qq = 0.f;
#pragma unroll
                for (int ww = 0; ww < 4; ++ww) { float2 t = red[ww * 32 + tid]; ss += t.x; qq += t.y; }
                float mu = ss * (1.f / 256.f);
                float var = qq * (1.f / 256.f) - mu * mu;
                muv[tid] = mu;
                rsv[tid] = 1.f / sqrtf(var + 1e-5f);
            }
            LGKBAR();
#pragma unroll
            for (int mt = 0; mt < 2; ++mt)
#pragma unroll
                for (int r = 0; r < 4; ++r) {
                    int rl = mt * 16 + quad * 4 + r;
                    float mu = muv[rl], rs = rsv[rl], we = wl[rl * 4 + e];
#pragma unroll
                    for (int nt = 0; nt < 4; ++nt) {
                        float y = (acc[mt][nt][r] - mu) * rs * egv[nt] + ebv[nt];
                        oacc[mt][nt][r] += we * y;
                        acc[mt][nt][r] = 0.f;    // reset for next expert
                    }
                }
        }
    }
#pragma unroll
    for (int mt = 0; mt < 2; ++mt)
#pragma unroll
        for (int r = 0; r < 4; ++r) {
            int rl = mt * 16 + quad * 4 + r;
#pragma unroll
            for (int nt = 0; nt < 4; ++nt) {
                int col = w * 64 + nt * 16 + l16;
                outp[(size_t)(m0 + rl) * 256 + col] = oacc[mt][nt][r];
            }
        }
}

// ---------------------------------------------------------------------------
extern "C" void kernel_launch(void* const* d_in, const int* in_sizes, int n_in,
                              void* d_out, int out_size, void* d_ws, size_t ws_size,
                              hipStream_t stream) {
    const float* vis   = (const float*)d_in[0];
    const float* lang  = (const float*)d_in[1];
    const float* state = (const float*)d_in[2];
    const float* Wf    = (const float*)d_in[3];
    const float* bf_   = (const float*)d_in[4];
    const float* gf    = (const float*)d_in[5];
    const float* bfln  = (const float*)d_in[6];
    const float* Wg    = (const float*)d_in[7];
    const float* W1    = (const float*)d_in[8];
    const float* b1    = (const float*)d_in[9];
    const float* W2    = (const float*)d_in[10];
    const float* b2    = (const float*)d_in[11];
    const float* W3    = (const float*)d_in[12];
    const float* b3    = (const float*)d_in[13];
    const float* eg    = (const float*)d_in[14];
    const float* eb    = (const float*)d_in[15];
    float* outp = (float*)d_out;

    char* ws = (char*)d_ws;
    size_t off = 0;
    float* lbacc = (float*)(ws + off); off += 256;
    u16* WFT  = (u16*)(ws + off); off += 819200UL;     // WfT [256][1600]
    u16* W1T  = (u16*)(ws + off); off += 1048576UL;    // [E][512][256]
    u16* W2T  = (u16*)(ws + off); off += 1048576UL;    // [E][256][512]
    u16* W3T  = (u16*)(ws + off); off += 524288UL;     // [E][256][256]
    u16* XBF  = (u16*)(ws + off); off += 8388608UL;    // x bf16 [B][256]
    float* WR = (float*)(ws + off); off += 262144UL;   // gate weights [B][4]
    u16* H1   = (u16*)(ws + off); off += 67108864UL;   // [E][B][512]
    u16* H2   = (u16*)(ws + off); off += 33554432UL;   // [E][B][256]
    if (ws_size < off) return;

    int prep_blocks = (PREP_ITEMS + 255) / 256;
    prep_kernel<<<prep_blocks, 256, 0, stream>>>(Wf, W1, W2, W3, WFT, W1T, W2T, W3T, lbacc);
    fusion_kernel<<<512, 256, 0, stream>>>(vis, lang, state, WFT, bf_, gf, bfln, Wg,
                                           XBF, WR, lbacc);
    expert_gemm_kernel<<<dim3(256, 2, 4), 256, 0, stream>>>(
        XBF, 256, 0, W1T, 131072, b1, 512, H1, 512, 8388608UL);
    expert_gemm_kernel<<<dim3(256, 1, 4), 256, 0, stream>>>(
        H1, 512, 8388608UL, W2T, 131072, b2, 256, H2, 256, 4194304UL);
    combine_kernel<<<512, 256, 0, stream>>>(H2, W3T, b3, eg, eb, XBF, WR, lbacc, outp);
}

// Round 2
// 343.147 us; speedup vs baseline: 1.0370x; 1.0370x over previous
//
#include <hip/hip_runtime.h>
#include <math.h>

// ---------------------------------------------------------------------------
// FusionMoE R4: single-barrier double-buffer pipeline with DISTINCT static
// LDS arrays (AA-disambiguable vs LDS-DMA writes) and compile-time buffer
// selection (manual 2x unroll). Pattern per K-step:
//     stage(next buf) -> compute(cur buf) -> __syncthreads()
// __syncthreads' vmcnt(0)+barrier after compute IS the T3 drain: load latency
// overlaps compute, one barrier per step. No inline asm. Math identical to R2.
// ---------------------------------------------------------------------------

typedef unsigned short u16;
typedef unsigned int u32;
typedef __attribute__((ext_vector_type(8))) short bf16x8;
typedef __attribute__((ext_vector_type(4))) float f32x4;

__device__ __forceinline__ float bf2f(u16 u) {
    union { u32 i; float f; } v; v.i = ((u32)u) << 16; return v.f;
}
__device__ __forceinline__ u16 f2bf(float f) {  // RNE
    union { float f; u32 i; } v; v.f = f;
    u32 x = v.i;
    return (u16)((x + 0x7fffu + ((x >> 16) & 1u)) >> 16);
}
__device__ __forceinline__ float gelu_exact(float v) {
    return 0.5f * v * (1.0f + erff(v * 0.70710678118654752f));
}

typedef __attribute__((address_space(1))) void GV;
typedef __attribute__((address_space(3))) void SV;
__device__ __forceinline__ void gldlds(const void* g, void* l) {
    __builtin_amdgcn_global_load_lds((GV*)g, (SV*)l, 16, 0, 0);
}

// pack two f32 (bit-truncate) into one u32 of two bf16 (f0 low, f1 high)
__device__ __forceinline__ u32 pk2(u32 f0, u32 f1) {
    return __builtin_amdgcn_perm(f1, f0, 0x07060302);
}

// ----- bf16 staging helpers (XOR-8 swizzle), verified in R1 -----
__device__ __forceinline__ void stageA64(const u16* Ag, int lda, u16* As, int tid) {
#pragma unroll
    for (int i = 0; i < 2; ++i) {
        int s = i * 256 + tid;          // 512 slots (64 rows x 8 chunks of 16B)
        int m = s >> 3, c = s & 7;
        gldlds(Ag + m * lda + (c ^ (m & 7)) * 8, As + s * 8);
    }
}
__device__ __forceinline__ void stageA64_R32(const u16* Ag, int lda, u16* As, int tid) {
    int s = tid;                        // 256 slots (32 rows x 8 chunks)
    int m = s >> 3, c = s & 7;
    gldlds(Ag + m * lda + (c ^ (m & 7)) * 8, As + s * 8);
}
__device__ __forceinline__ void stageB64(const u16* Bg, int ldb, u16* Bs, int tid) {
#pragma unroll
    for (int i = 0; i < 8; ++i) {
        int s = i * 256 + tid;          // 2048 slots (256 n-rows x 8 chunks)
        int n = s >> 3, c = s & 7;
        gldlds(Bg + n * ldb + (c ^ (n & 7)) * 8, Bs + s * 8);
    }
}
__device__ __forceinline__ void compute64(const u16* As, const u16* Bs, f32x4 acc[4][4],
                                          int w, int l16, int quad) {
#pragma unroll
    for (int ks = 0; ks < 2; ++ks) {
        bf16x8 a[4];
#pragma unroll
        for (int mt = 0; mt < 4; ++mt) {
            int m = mt * 16 + l16;
            a[mt] = *(const bf16x8*)(As + m * 64 + (((ks * 4 + quad) ^ (m & 7)) << 3));
        }
#pragma unroll
        for (int nt = 0; nt < 4; ++nt) {
            int n = w * 64 + nt * 16 + l16;
            bf16x8 b = *(const bf16x8*)(Bs + n * 64 + (((ks * 4 + quad) ^ (n & 7)) << 3));
#pragma unroll
            for (int mt = 0; mt < 4; ++mt)
                acc[mt][nt] = __builtin_amdgcn_mfma_f32_16x16x32_bf16(a[mt], b, acc[mt][nt], 0, 0, 0);
        }
    }
}
__device__ __forceinline__ void compute64_R32(const u16* As, const u16* Bs, f32x4 acc[2][4],
                                              int w, int l16, int quad) {
#pragma unroll
    for (int ks = 0; ks < 2; ++ks) {
        bf16x8 a[2];
#pragma unroll
        for (int mt = 0; mt < 2; ++mt) {
            int m = mt * 16 + l16;
            a[mt] = *(const bf16x8*)(As + m * 64 + (((ks * 4 + quad) ^ (m & 7)) << 3));
        }
#pragma unroll
        for (int nt = 0; nt < 4; ++nt) {
            int n = w * 64 + nt * 16 + l16;
            bf16x8 b = *(const bf16x8*)(Bs + n * 64 + (((ks * 4 + quad) ^ (n & 7)) << 3));
#pragma unroll
            for (int mt = 0; mt < 2; ++mt)
                acc[mt][nt] = __builtin_amdgcn_mfma_f32_16x16x32_bf16(a[mt], b, acc[mt][nt], 0, 0, 0);
        }
    }
}

// ---------------------------------------------------------------------------
// K0: prep — weight transposes to bf16 + lbacc zero (weights only, ~7 MB)
// ---------------------------------------------------------------------------
#define SEG_WF  409600
#define SEG_W1  524288
#define SEG_W2  524288
#define SEG_W3  262144
#define PREP_ITEMS (SEG_WF + SEG_W1 + SEG_W2 + SEG_W3 + 8)

__global__ __launch_bounds__(256) void prep_kernel(
    const float* __restrict__ Wf, const float* __restrict__ W1, const float* __restrict__ W2,
    const float* __restrict__ W3,
    u16* __restrict__ wft, u16* __restrict__ w1t, u16* __restrict__ w2t, u16* __restrict__ w3t,
    float* __restrict__ lbacc) {
    int idx = blockIdx.x * 256 + threadIdx.x;
    if (idx < SEG_WF) {  // WfT[n<256][k<1600] = Wf[k][n]
        int n = idx / 1600, k = idx % 1600;
        wft[idx] = f2bf(Wf[(size_t)k * 256 + n]);
        return;
    }
    idx -= SEG_WF;
    if (idx < SEG_W1) {  // W1T[e][n<512][k<256] = W1[e][k][n]
        int e = idx >> 17, r = idx & 131071;
        int n = r >> 8, k = r & 255;
        w1t[idx] = f2bf(W1[(size_t)e * 131072 + (size_t)k * 512 + n]);
        return;
    }
    idx -= SEG_W1;
    if (idx < SEG_W2) {  // W2T[e][n<256][k<512] = W2[e][k][n]
        int e = idx >> 17, r = idx & 131071;
        int n = r >> 9, k = r & 511;
        w2t[idx] = f2bf(W2[(size_t)e * 131072 + (size_t)k * 256 + n]);
        return;
    }
    idx -= SEG_W2;
    if (idx < SEG_W3) {  // W3T[e][n<256][k<256] = W3[e][k][n]
        int e = idx >> 16, r = idx & 65535;
        int n = r >> 8, k = r & 255;
        w3t[idx] = f2bf(W3[(size_t)e * 65536 + (size_t)k * 256 + n]);
        return;
    }
    idx -= SEG_W3;
    if (idx < 8) lbacc[idx] = 0.0f;
}

// ---------------------------------------------------------------------------
// K1: fusion — fp32 A direct, bf16 B, 32x256 tile, dbuf pipeline (distinct
// arrays). Epilogue: bias+LN+GELU -> xbf, fused gate -> wr + lb atomics
// ---------------------------------------------------------------------------
__global__ __launch_bounds__(256) void fusion_kernel(
    const float* __restrict__ vis, const float* __restrict__ lang, const float* __restrict__ state,
    const u16* __restrict__ BT, const float* __restrict__ bfv_, const float* __restrict__ gf,
    const float* __restrict__ bfln, const float* __restrict__ Wg,
    u16* __restrict__ xbf, float* __restrict__ wr, float* __restrict__ lbacc) {
    __shared__ __align__(16) u32 AfA[2048];     // 8KB: 32 rows x 16 f32-chunks (XOR-16)
    __shared__ __align__(16) u32 AfB[2048];
    __shared__ __align__(16) u16 BsA[16384];    // 32KB: 256 n x 64 k bf16
    __shared__ __align__(16) u16 BsB[16384];
    int tid = threadIdx.x;
    int w = tid >> 6, lane = tid & 63, quad = lane >> 4, l16 = lane & 15;
    int m0 = blockIdx.x * 32;
    f32x4 acc[2][4] = {};

    auto stageK = [&](u32* Af, u16* Bs, int kit) {
        const float* base; int ld;
        if (kit < 12)      { base = vis   + (size_t)m0 * 768 + kit * 64;        ld = 768; }
        else if (kit < 24) { base = lang  + (size_t)m0 * 768 + (kit - 12) * 64; ld = 768; }
        else               { base = state + (size_t)m0 * 64;                    ld = 64; }
#pragma unroll
        for (int i = 0; i < 2; ++i) {        // A: 512 slots of 16B (4 f32)
            int s = i * 256 + tid;
            int m = s >> 4, c = s & 15;
            gldlds(base + m * ld + (c ^ (m & 15)) * 4, Af + s * 4);
        }
        stageB64(BT + kit * 64, 1600, Bs, tid);  // 8 loads
    };
    auto computeK = [&](const u32* Af, const u16* Bs) {
#pragma unroll
        for (int ks = 0; ks < 2; ++ks) {
            bf16x8 a[2];
#pragma unroll
            for (int mt = 0; mt < 2; ++mt) {
                int m = mt * 16 + l16;
                int c0 = ks * 8 + quad * 2;
                const u32* rowp = Af + m * 64;
                uint4 f0 = *(const uint4*)(rowp + (c0 ^ (m & 15)) * 4);
                uint4 f1 = *(const uint4*)(rowp + ((c0 + 1) ^ (m & 15)) * 4);
                union { u32 u[4]; bf16x8 v; } pk;
                pk.u[0] = pk2(f0.x, f0.y); pk.u[1] = pk2(f0.z, f0.w);
                pk.u[2] = pk2(f1.x, f1.y); pk.u[3] = pk2(f1.z, f1.w);
                a[mt] = pk.v;
            }
#pragma unroll
            for (int nt = 0; nt < 4; ++nt) {
                int n = w * 64 + nt * 16 + l16;
                bf16x8 b = *(const bf16x8*)(Bs + n * 64 + (((ks * 4 + quad) ^ (n & 7)) << 3));
#pragma unroll
                for (int mt = 0; mt < 2; ++mt)
                    acc[mt][nt] = __builtin_amdgcn_mfma_f32_16x16x32_bf16(a[mt], b, acc[mt][nt], 0, 0, 0);
            }
        }
    };

    stageK(AfA, BsA, 0);
    __syncthreads();
    for (int kit = 0; kit < 24; kit += 2) {
        stageK(AfB, BsB, kit + 1);        // issue next while computing cur
        computeK(AfA, BsA);
        __syncthreads();                  // drains B-stage (overlapped by compute)
        if (kit + 2 < 25) stageK(AfA, BsA, kit + 2);
        computeK(AfB, BsB);
        __syncthreads();
    }
    computeK(AfA, BsA);                   // kit = 24
    __syncthreads();                      // guard epilogue LDS reuse

    // ---- epilogue: bias, LN, GELU, xbf store, fused gate ----
    u32* Af0 = AfA;
    float2* red  = (float2*)Af0;           // 128 float2 (w*32+rl)
    float*  muv  = (float*)(Af0 + 256);    // 32
    float*  rsv  = (float*)(Af0 + 288);    // 32
    float*  gred = (float*)(Af0 + 512);    // 512: [w][rl][e]
    float*  sacc = (float*)(Af0 + 1024);   // 8

    float bv[4], gvv[4], blv[4]; float4 wgv[4];
#pragma unroll
    for (int nt = 0; nt < 4; ++nt) {
        int col = w * 64 + nt * 16 + l16;
        bv[nt] = bfv_[col]; gvv[nt] = gf[col]; blv[nt] = bfln[col];
        wgv[nt] = *(const float4*)(Wg + col * 4);
    }
    if (tid < 8) sacc[tid] = 0.f;
#pragma unroll
    for (int mt = 0; mt < 2; ++mt)
#pragma unroll
        for (int r = 0; r < 4; ++r) {
            float ss = 0.f, qq = 0.f;
#pragma unroll
            for (int nt = 0; nt < 4; ++nt) {
                float v = acc[mt][nt][r] + bv[nt];
                acc[mt][nt][r] = v;
                ss += v; qq += v * v;
            }
#pragma unroll
            for (int d = 1; d < 16; d <<= 1) { ss += __shfl_xor(ss, d); qq += __shfl_xor(qq, d); }
            if (l16 == 0) red[w * 32 + mt * 16 + quad * 4 + r] = make_float2(ss, qq);
        }
    __syncthreads();
    if (tid < 32) {
        float ss = 0.f, qq = 0.f;
#pragma unroll
        for (int ww = 0; ww < 4; ++ww) { float2 t = red[ww * 32 + tid]; ss += t.x; qq += t.y; }
        float mu = ss * (1.f / 256.f);
        float var = qq * (1.f / 256.f) - mu * mu;
        muv[tid] = mu;
        rsv[tid] = 1.f / sqrtf(var + 1e-5f);
    }
    __syncthreads();
#pragma unroll
    for (int mt = 0; mt < 2; ++mt)
#pragma unroll
        for (int r = 0; r < 4; ++r) {
            int rl = mt * 16 + quad * 4 + r;
            float mu = muv[rl], rs = rsv[rl];
#pragma unroll
            for (int nt = 0; nt < 4; ++nt) {
                int col = w * 64 + nt * 16 + l16;
                float t = (acc[mt][nt][r] - mu) * rs * gvv[nt] + blv[nt];
                float g = gelu_exact(t);
                acc[mt][nt][r] = g;
                xbf[(size_t)(m0 + rl) * 256 + col] = f2bf(g);
            }
        }
    // gate partials (fp32 x, pre-bf16-truncation)
#pragma unroll
    for (int mt = 0; mt < 2; ++mt)
#pragma unroll
        for (int r = 0; r < 4; ++r) {
            int rl = mt * 16 + quad * 4 + r;
            float p0 = 0.f, p1 = 0.f, p2 = 0.f, p3 = 0.f;
#pragma unroll
            for (int nt = 0; nt < 4; ++nt) {
                float g = acc[mt][nt][r];
                p0 += g * wgv[nt].x; p1 += g * wgv[nt].y;
                p2 += g * wgv[nt].z; p3 += g * wgv[nt].w;
            }
#pragma unroll
            for (int d = 1; d < 16; d <<= 1) {
                p0 += __shfl_xor(p0, d); p1 += __shfl_xor(p1, d);
                p2 += __shfl_xor(p2, d); p3 += __shfl_xor(p3, d);
            }
            if (l16 == 0) {
                float* gp = gred + w * 128 + rl * 4;
                gp[0] = p0; gp[1] = p1; gp[2] = p2; gp[3] = p3;
            }
        }
    __syncthreads();
    if (tid < 32) {
        int row = tid;
        float lg[4];
#pragma unroll
        for (int e = 0; e < 4; ++e)
            lg[e] = gred[row * 4 + e] + gred[128 + row * 4 + e] +
                    gred[256 + row * 4 + e] + gred[384 + row * 4 + e];
        float mx = fmaxf(fmaxf(lg[0], lg[1]), fmaxf(lg[2], lg[3]));
        float ex[4]; float Z = 0.f;
#pragma unroll
        for (int e = 0; e < 4; ++e) { ex[e] = expf(lg[e] - mx); Z += ex[e]; }
        int i0 = 0; float v0 = lg[0];
#pragma unroll
        for (int e = 1; e < 4; ++e) if (lg[e] > v0) { v0 = lg[e]; i0 = e; }
        int i1 = -1; float v1 = -1e30f;
#pragma unroll
        for (int e = 0; e < 4; ++e) if (e != i0 && lg[e] > v1) { v1 = lg[e]; i1 = e; }
        float t = expf(v1 - v0);
        float wA = 1.f / (1.f + t), wB = t / (1.f + t);
        float w4[4] = {0.f, 0.f, 0.f, 0.f};
        w4[i0] = wA; w4[i1] = wB;
#pragma unroll
        for (int e = 0; e < 4; ++e) wr[(size_t)(m0 + row) * 4 + e] = w4[e];
#pragma unroll
        for (int e = 0; e < 4; ++e) atomicAdd(&sacc[e], ex[e] / Z);
        atomicAdd(&sacc[4 + i0], 1.f);
        atomicAdd(&sacc[4 + i1], 1.f);
    }
    __syncthreads();
    if (tid < 8) atomicAdd(lbacc + tid, sacc[tid]);
}

// ---------------------------------------------------------------------------
// K2: expert GEMM + bias + GELU, batched over blockIdx.z = expert.
// Distinct-array dbuf pipeline, one barrier per K-step. kiters is even.
// ---------------------------------------------------------------------------
__global__ __launch_bounds__(256) void expert_gemm_kernel(
    const u16* __restrict__ A, int lda, size_t aE,
    const u16* __restrict__ BT, size_t bE,
    const float* __restrict__ bias, int biasE,
    u16* __restrict__ outp, int ldo, size_t oE) {
    __shared__ __align__(16) u16 AsA[4096];
    __shared__ __align__(16) u16 AsB[4096];
    __shared__ __align__(16) u16 BsA[16384];
    __shared__ __align__(16) u16 BsB[16384];
    int tid = threadIdx.x;
    int w = tid >> 6, lane = tid & 63, quad = lane >> 4, l16 = lane & 15;
    int m0 = blockIdx.x * 64;
    int col0 = blockIdx.y * 256;
    int e = blockIdx.z;
    f32x4 acc[4][4] = {};
    const u16* Ag = A + e * aE + (size_t)m0 * lda;
    const u16* Bg = BT + e * bE + (size_t)col0 * lda;
    int kiters = lda >> 6;
    stageA64(Ag, lda, AsA, tid);
    stageB64(Bg, lda, BsA, tid);
    __syncthreads();
    for (int kit = 0; kit < kiters; kit += 2) {
        stageA64(Ag + (kit + 1) * 64, lda, AsB, tid);
        stageB64(Bg + (kit + 1) * 64, lda, BsB, tid);
        compute64(AsA, BsA, acc, w, l16, quad);
        __syncthreads();
        if (kit + 2 < kiters) {
            stageA64(Ag + (kit + 2) * 64, lda, AsA, tid);
            stageB64(Bg + (kit + 2) * 64, lda, BsA, tid);
        }
        compute64(AsB, BsB, acc, w, l16, quad);
        __syncthreads();
    }
#pragma unroll
    for (int nt = 0; nt < 4; ++nt) {
        int col = col0 + w * 64 + nt * 16 + l16;
        float bvv = bias[e * biasE + col];
#pragma unroll
        for (int mt = 0; mt < 4; ++mt)
#pragma unroll
            for (int r = 0; r < 4; ++r) {
                int row = m0 + mt * 16 + quad * 4 + r;
                outp[e * oE + (size_t)row * ldo + col] = f2bf(gelu_exact(acc[mt][nt][r] + bvv));
            }
    }
}

// ---------------------------------------------------------------------------
// K3: combine — 32-row tiles; dbuf pipeline across all 16 (e,kit) steps;
// x in regs. h2@W3 + b3 + x -> LN -> *eg+eb, out += w[row][e]*y; lb by blk 0.
// ---------------------------------------------------------------------------
__global__ __launch_bounds__(256) void combine_kernel(
    const u16* __restrict__ h2, const u16* __restrict__ W3T,
    const float* __restrict__ b3, const float* __restrict__ eg, const float* __restrict__ eb,
    const u16* __restrict__ xbf, const float* __restrict__ wr,
    const float* __restrict__ lbacc, float* __restrict__ outp) {
    __shared__ __align__(16) u16 AsA[2048];     // 4KB: 32 rows x 64 k
    __shared__ __align__(16) u16 AsB[2048];
    __shared__ __align__(16) u16 BsA[16384];    // 32KB
    __shared__ __align__(16) u16 BsB[16384];
    __shared__ float wl[128];
    __shared__ float2 red[128];
    __shared__ float muv[32], rsv[32];
    int tid = threadIdx.x;
    int w = tid >> 6, lane = tid & 63, quad = lane >> 4, l16 = lane & 15;
    int m0 = blockIdx.x * 32;
    if (blockIdx.x == 0 && tid == 0) {          // lb_loss (lbacc complete: fusion done)
        float lb = 0.f;
#pragma unroll
        for (int e = 0; e < 4; ++e)
            lb += (lbacc[4 + e] / 32768.f) * (lbacc[e] / 16384.f);
        outp[4194304] = 4.f * lb;
    }
    // ---- x tile -> registers (bounce through BsA, then BsA reused) ----
    u16* xs = BsA;
#pragma unroll
    for (int i = 0; i < 4; ++i) {
        int s = i * 256 + tid;
        *(uint4*)(xs + s * 8) = *(const uint4*)(xbf + (size_t)m0 * 256 + s * 8);
    }
    if (tid < 128) wl[tid] = wr[(size_t)m0 * 4 + tid];
    __syncthreads();
    float xr[2][4][4];
#pragma unroll
    for (int mt = 0; mt < 2; ++mt)
#pragma unroll
        for (int r = 0; r < 4; ++r) {
            int rl = mt * 16 + quad * 4 + r;
#pragma unroll
            for (int nt = 0; nt < 4; ++nt) {
                int col = w * 64 + nt * 16 + l16;
                xr[mt][r][nt] = bf2f(xs[rl * 256 + col]);
            }
        }
    __syncthreads();                            // x reads done; BsA free

    f32x4 oacc[2][4] = {};
    f32x4 acc[2][4] = {};
    auto stageP = [&](u16* As, u16* Bs, int p) {  // p = e*4 + kit
        int ee = p >> 2, kit = p & 3;
        stageA64_R32(h2 + ((size_t)ee * 16384 + m0) * 256 + kit * 64, 256, As, tid);
        stageB64(W3T + (size_t)ee * 65536 + kit * 64, 256, Bs, tid);
    };
    auto epilogue = [&](int e) {
        float b3v[4], egv[4], ebv[4];
#pragma unroll
        for (int nt = 0; nt < 4; ++nt) {
            int col = w * 64 + nt * 16 + l16;
            b3v[nt] = b3[e * 256 + col]; egv[nt] = eg[e * 256 + col]; ebv[nt] = eb[e * 256 + col];
        }
#pragma unroll
        for (int mt = 0; mt < 2; ++mt)
#pragma unroll
            for (int r = 0; r < 4; ++r) {
                int rl = mt * 16 + quad * 4 + r;
                float ss = 0.f, qq = 0.f;
#pragma unroll
                for (int nt = 0; nt < 4; ++nt) {
                    float v = acc[mt][nt][r] + b3v[nt] + xr[mt][r][nt];
                    acc[mt][nt][r] = v;
                    ss += v; qq += v * v;
                }
#pragma unroll
                for (int d = 1; d < 16; d <<= 1) { ss += __shfl_xor(ss, d); qq += __shfl_xor(qq, d); }
                if (l16 == 0) red[w * 32 + rl] = make_float2(ss, qq);
            }
        __syncthreads();
        if (tid < 32) {
            float ss = 0.f, qq = 0.f;
#pragma unroll
            for (int ww = 0; ww < 4; ++ww) { float2 t = red[ww * 32 + tid]; ss += t.x; qq += t.y; }
            float mu = ss * (1.f / 256.f);
            float var = qq * (1.f / 256.f) - mu * mu;
            muv[tid] = mu;
            rsv[tid] = 1.f / sqrtf(var + 1e-5f);
        }
        __syncthreads();
#pragma unroll
        for (int mt = 0; mt < 2; ++mt)
#pragma unroll
            for (int r = 0; r < 4; ++r) {
                int rl = mt * 16 + quad * 4 + r;
                float mu = muv[rl], rs = rsv[rl], we = wl[rl * 4 + e];
#pragma unroll
                for (int nt = 0; nt < 4; ++nt) {
                    float y = (acc[mt][nt][r] - mu) * rs * egv[nt] + ebv[nt];
                    oacc[mt][nt][r] += we * y;
                    acc[mt][nt][r] = 0.f;       // reset for next expert
                }
            }
    };

    stageP(AsA, BsA, 0);
    __syncthreads();
    for (int p = 0; p < 16; p += 2) {
        stageP(AsB, BsB, p + 1);
        compute64_R32(AsA, BsA, acc, w, l16, quad);
        __syncthreads();
        if (p + 2 < 16) stageP(AsA, BsA, p + 2);
        compute64_R32(AsB, BsB, acc, w, l16, quad);
        __syncthreads();
        if ((p & 3) == 2) epilogue(p >> 2);     // experts finish at steps 3,7,11,15
    }
#pragma unroll
    for (int mt = 0; mt < 2; ++mt)
#pragma unroll
        for (int r = 0; r < 4; ++r) {
            int rl = mt * 16 + quad * 4 + r;
#pragma unroll
            for (int nt = 0; nt < 4; ++nt) {
                int col = w * 64 + nt * 16 + l16;
                outp[(size_t)(m0 + rl) * 256 + col] = oacc[mt][nt][r];
            }
        }
}

// ---------------------------------------------------------------------------
extern "C" void kernel_launch(void* const* d_in, const int* in_sizes, int n_in,
                              void* d_out, int out_size, void* d_ws, size_t ws_size,
                              hipStream_t stream) {
    const float* vis   = (const float*)d_in[0];
    const float* lang  = (const float*)d_in[1];
    const float* state = (const float*)d_in[2];
    const float* Wf    = (const float*)d_in[3];
    const float* bf_   = (const float*)d_in[4];
    const float* gf    = (const float*)d_in[5];
    const float* bfln  = (const float*)d_in[6];
    const float* Wg    = (const float*)d_in[7];
    const float* W1    = (const float*)d_in[8];
    const float* b1    = (const float*)d_in[9];
    const float* W2    = (const float*)d_in[10];
    const float* b2    = (const float*)d_in[11];
    const float* W3    = (const float*)d_in[12];
    const float* b3    = (const float*)d_in[13];
    const float* eg    = (const float*)d_in[14];
    const float* eb    = (const float*)d_in[15];
    float* outp = (float*)d_out;

    char* ws = (char*)d_ws;
    size_t off = 0;
    float* lbacc = (float*)(ws + off); off += 256;
    u16* WFT  = (u16*)(ws + off); off += 819200UL;     // WfT [256][1600]
    u16* W1T  = (u16*)(ws + off); off += 1048576UL;    // [E][512][256]
    u16* W2T  = (u16*)(ws + off); off += 1048576UL;    // [E][256][512]
    u16* W3T  = (u16*)(ws + off); off += 524288UL;     // [E][256][256]
    u16* XBF  = (u16*)(ws + off); off += 8388608UL;    // x bf16 [B][256]
    float* WR = (float*)(ws + off); off += 262144UL;   // gate weights [B][4]
    u16* H1   = (u16*)(ws + off); off += 67108864UL;   // [E][B][512]
    u16* H2   = (u16*)(ws + off); off += 33554432UL;   // [E][B][256]
    if (ws_size < off) return;

    int prep_blocks = (PREP_ITEMS + 255) / 256;
    prep_kernel<<<prep_blocks, 256, 0, stream>>>(Wf, W1, W2, W3, WFT, W1T, W2T, W3T, lbacc);
    fusion_kernel<<<512, 256, 0, stream>>>(vis, lang, state, WFT, bf_, gf, bfln, Wg,
                                           XBF, WR, lbacc);
    expert_gemm_kernel<<<dim3(256, 2, 4), 256, 0, stream>>>(
        XBF, 256, 0, W1T, 131072, b1, 512, H1, 512, 8388608UL);
    expert_gemm_kernel<<<dim3(256, 1, 4), 256, 0, stream>>>(
        H1, 512, 8388608UL, W2T, 131072, b2, 256, H2, 256, 4194304UL);
    combine_kernel<<<512, 256, 0, stream>>>(H2, W3T, b3, eg, eb, XBF, WR, lbacc, outp);
}

// Round 3
// 342.430 us; speedup vs baseline: 1.0392x; 1.0021x over previous
//
#include <hip/hip_runtime.h>
#include <math.h>

// ---------------------------------------------------------------------------
// FusionMoE R5: true cross-barrier prefetch. Distinct static LDS buffers
// (AA-disambiguable, compile-time selected via manual 2x unroll) + counted
// s_waitcnt vmcnt(N) + raw s_barrier, so the next tile's global_load_lds
// stay in flight while the current tile computes. Post-compute barrier is
// lgkmcnt(0)+s_barrier (closes ds_read vs re-stage DMA race, rule #18).
// combine's per-expert LN epilogue uses lgkm-only barriers -> overlaps the
// next expert's prefetch. Math identical to R2.
// ---------------------------------------------------------------------------

typedef unsigned short u16;
typedef unsigned int u32;
typedef __attribute__((ext_vector_type(8))) short bf16x8;
typedef __attribute__((ext_vector_type(4))) float f32x4;

__device__ __forceinline__ float bf2f(u16 u) {
    union { u32 i; float f; } v; v.i = ((u32)u) << 16; return v.f;
}
__device__ __forceinline__ u16 f2bf(float f) {  // RNE
    union { float f; u32 i; } v; v.f = f;
    u32 x = v.i;
    return (u16)((x + 0x7fffu + ((x >> 16) & 1u)) >> 16);
}
__device__ __forceinline__ float gelu_exact(float v) {
    return 0.5f * v * (1.0f + erff(v * 0.70710678118654752f));
}

typedef __attribute__((address_space(1))) void GV;
typedef __attribute__((address_space(3))) void SV;
__device__ __forceinline__ void gldlds(const void* g, void* l) {
    __builtin_amdgcn_global_load_lds((GV*)g, (SV*)l, 16, 0, 0);
}

// pack two f32 (bit-truncate) into one u32 of two bf16 (f0 low, f1 high)
__device__ __forceinline__ u32 pk2(u32 f0, u32 f1) {
    return __builtin_amdgcn_perm(f1, f0, 0x07060302);
}

// counted-vmcnt wait: allow N loads to remain in flight
#define WAIT_VM(N) asm volatile("s_waitcnt vmcnt(" #N ")" ::: "memory")
// raw barrier (no vmcnt drain) — each wave must WAIT_VM its own loads first
#define BARRIER()                                    \
    do {                                             \
        asm volatile("" ::: "memory");               \
        __builtin_amdgcn_s_barrier();                \
        asm volatile("" ::: "memory");               \
    } while (0)
// post-compute barrier: drain LDS ops only, keep prefetch vmcnt in flight
#define LGKBAR()                                            \
    do {                                                    \
        asm volatile("s_waitcnt lgkmcnt(0)" ::: "memory");  \
        __builtin_amdgcn_s_barrier();                       \
        asm volatile("" ::: "memory");                      \
    } while (0)

// ----- bf16 staging helpers (XOR-8 swizzle), verified in R1 -----
__device__ __forceinline__ void stageA64(const u16* Ag, int lda, u16* As, int tid) {
#pragma unroll
    for (int i = 0; i < 2; ++i) {
        int s = i * 256 + tid;          // 512 slots (64 rows x 8 chunks of 16B)
        int m = s >> 3, c = s & 7;
        gldlds(Ag + m * lda + (c ^ (m & 7)) * 8, As + s * 8);
    }
}
__device__ __forceinline__ void stageA64_R32(const u16* Ag, int lda, u16* As, int tid) {
    int s = tid;                        // 256 slots (32 rows x 8 chunks)
    int m = s >> 3, c = s & 7;
    gldlds(Ag + m * lda + (c ^ (m & 7)) * 8, As + s * 8);
}
__device__ __forceinline__ void stageB64(const u16* Bg, int ldb, u16* Bs, int tid) {
#pragma unroll
    for (int i = 0; i < 8; ++i) {
        int s = i * 256 + tid;          // 2048 slots (256 n-rows x 8 chunks)
        int n = s >> 3, c = s & 7;
        gldlds(Bg + n * ldb + (c ^ (n & 7)) * 8, Bs + s * 8);
    }
}
__device__ __forceinline__ void compute64(const u16* As, const u16* Bs, f32x4 acc[4][4],
                                          int w, int l16, int quad) {
#pragma unroll
    for (int ks = 0; ks < 2; ++ks) {
        bf16x8 a[4];
#pragma unroll
        for (int mt = 0; mt < 4; ++mt) {
            int m = mt * 16 + l16;
            a[mt] = *(const bf16x8*)(As + m * 64 + (((ks * 4 + quad) ^ (m & 7)) << 3));
        }
#pragma unroll
        for (int nt = 0; nt < 4; ++nt) {
            int n = w * 64 + nt * 16 + l16;
            bf16x8 b = *(const bf16x8*)(Bs + n * 64 + (((ks * 4 + quad) ^ (n & 7)) << 3));
#pragma unroll
            for (int mt = 0; mt < 4; ++mt)
                acc[mt][nt] = __builtin_amdgcn_mfma_f32_16x16x32_bf16(a[mt], b, acc[mt][nt], 0, 0, 0);
        }
    }
}
__device__ __forceinline__ void compute64_R32(const u16* As, const u16* Bs, f32x4 acc[2][4],
                                              int w, int l16, int quad) {
#pragma unroll
    for (int ks = 0; ks < 2; ++ks) {
        bf16x8 a[2];
#pragma unroll
        for (int mt = 0; mt < 2; ++mt) {
            int m = mt * 16 + l16;
            a[mt] = *(const bf16x8*)(As + m * 64 + (((ks * 4 + quad) ^ (m & 7)) << 3));
        }
#pragma unroll
        for (int nt = 0; nt < 4; ++nt) {
            int n = w * 64 + nt * 16 + l16;
            bf16x8 b = *(const bf16x8*)(Bs + n * 64 + (((ks * 4 + quad) ^ (n & 7)) << 3));
#pragma unroll
            for (int mt = 0; mt < 2; ++mt)
                acc[mt][nt] = __builtin_amdgcn_mfma_f32_16x16x32_bf16(a[mt], b, acc[mt][nt], 0, 0, 0);
        }
    }
}

// ---------------------------------------------------------------------------
// K0: prep — weight transposes to bf16 + lbacc zero (weights only, ~7 MB)
// ---------------------------------------------------------------------------
#define SEG_WF  409600
#define SEG_W1  524288
#define SEG_W2  524288
#define SEG_W3  262144
#define PREP_ITEMS (SEG_WF + SEG_W1 + SEG_W2 + SEG_W3 + 8)

__global__ __launch_bounds__(256) void prep_kernel(
    const float* __restrict__ Wf, const float* __restrict__ W1, const float* __restrict__ W2,
    const float* __restrict__ W3,
    u16* __restrict__ wft, u16* __restrict__ w1t, u16* __restrict__ w2t, u16* __restrict__ w3t,
    float* __restrict__ lbacc) {
    int idx = blockIdx.x * 256 + threadIdx.x;
    if (idx < SEG_WF) {  // WfT[n<256][k<1600] = Wf[k][n]
        int n = idx / 1600, k = idx % 1600;
        wft[idx] = f2bf(Wf[(size_t)k * 256 + n]);
        return;
    }
    idx -= SEG_WF;
    if (idx < SEG_W1) {  // W1T[e][n<512][k<256] = W1[e][k][n]
        int e = idx >> 17, r = idx & 131071;
        int n = r >> 8, k = r & 255;
        w1t[idx] = f2bf(W1[(size_t)e * 131072 + (size_t)k * 512 + n]);
        return;
    }
    idx -= SEG_W1;
    if (idx < SEG_W2) {  // W2T[e][n<256][k<512] = W2[e][k][n]
        int e = idx >> 17, r = idx & 131071;
        int n = r >> 9, k = r & 511;
        w2t[idx] = f2bf(W2[(size_t)e * 131072 + (size_t)k * 256 + n]);
        return;
    }
    idx -= SEG_W2;
    if (idx < SEG_W3) {  // W3T[e][n<256][k<256] = W3[e][k][n]
        int e = idx >> 16, r = idx & 65535;
        int n = r >> 8, k = r & 255;
        w3t[idx] = f2bf(W3[(size_t)e * 65536 + (size_t)k * 256 + n]);
        return;
    }
    idx -= SEG_W3;
    if (idx < 8) lbacc[idx] = 0.0f;
}

// ---------------------------------------------------------------------------
// K1: fusion — fp32 A direct, bf16 B, 32x256 tile, cross-barrier prefetch.
// Epilogue: bias+LN+GELU -> xbf, fused gate -> wr + lb atomics
// ---------------------------------------------------------------------------
__global__ __launch_bounds__(256) void fusion_kernel(
    const float* __restrict__ vis, const float* __restrict__ lang, const float* __restrict__ state,
    const u16* __restrict__ BT, const float* __restrict__ bfv_, const float* __restrict__ gf,
    const float* __restrict__ bfln, const float* __restrict__ Wg,
    u16* __restrict__ xbf, float* __restrict__ wr, float* __restrict__ lbacc) {
    __shared__ __align__(16) u32 AfA[2048];     // 8KB: 32 rows x 16 f32-chunks (XOR-16)
    __shared__ __align__(16) u32 AfB[2048];
    __shared__ __align__(16) u16 BsA[16384];    // 32KB: 256 n x 64 k bf16
    __shared__ __align__(16) u16 BsB[16384];
    int tid = threadIdx.x;
    int w = tid >> 6, lane = tid & 63, quad = lane >> 4, l16 = lane & 15;
    int m0 = blockIdx.x * 32;
    f32x4 acc[2][4] = {};

    auto stageK = [&](u32* Af, u16* Bs, int kit) {   // 10 loads/thread
        const float* base; int ld;
        if (kit < 12)      { base = vis   + (size_t)m0 * 768 + kit * 64;        ld = 768; }
        else if (kit < 24) { base = lang  + (size_t)m0 * 768 + (kit - 12) * 64; ld = 768; }
        else               { base = state + (size_t)m0 * 64;                    ld = 64; }
#pragma unroll
        for (int i = 0; i < 2; ++i) {        // A: 512 slots of 16B (4 f32)
            int s = i * 256 + tid;
            int m = s >> 4, c = s & 15;
            gldlds(base + m * ld + (c ^ (m & 15)) * 4, Af + s * 4);
        }
        stageB64(BT + kit * 64, 1600, Bs, tid);  // 8 loads
    };
    auto computeK = [&](const u32* Af, const u16* Bs) {
#pragma unroll
        for (int ks = 0; ks < 2; ++ks) {
            bf16x8 a[2];
#pragma unroll
            for (int mt = 0; mt < 2; ++mt) {
                int m = mt * 16 + l16;
                int c0 = ks * 8 + quad * 2;
                const u32* rowp = Af + m * 64;
                uint4 f0 = *(const uint4*)(rowp + (c0 ^ (m & 15)) * 4);
                uint4 f1 = *(const uint4*)(rowp + ((c0 + 1) ^ (m & 15)) * 4);
                union { u32 u[4]; bf16x8 v; } pk;
                pk.u[0] = pk2(f0.x, f0.y); pk.u[1] = pk2(f0.z, f0.w);
                pk.u[2] = pk2(f1.x, f1.y); pk.u[3] = pk2(f1.z, f1.w);
                a[mt] = pk.v;
            }
#pragma unroll
            for (int nt = 0; nt < 4; ++nt) {
                int n = w * 64 + nt * 16 + l16;
                bf16x8 b = *(const bf16x8*)(Bs + n * 64 + (((ks * 4 + quad) ^ (n & 7)) << 3));
#pragma unroll
                for (int mt = 0; mt < 2; ++mt)
                    acc[mt][nt] = __builtin_amdgcn_mfma_f32_16x16x32_bf16(a[mt], b, acc[mt][nt], 0, 0, 0);
            }
        }
    };

    stageK(AfA, BsA, 0);                       // 10 in flight
    for (int kit = 0; kit < 24; kit += 2) {
        stageK(AfB, BsB, kit + 1);             // 20 in flight
        WAIT_VM(10);                           // A done, B's 10 stay in flight
        BARRIER();
        computeK(AfA, BsA);
        LGKBAR();                              // ds_reads retired -> A re-stageable
        stageK(AfA, BsA, kit + 2);             // 20 in flight
        WAIT_VM(10);                           // B done, A's 10 stay in flight
        BARRIER();
        computeK(AfB, BsB);
        LGKBAR();
    }
    WAIT_VM(0);
    BARRIER();
    computeK(AfA, BsA);                        // kit = 24
    __syncthreads();                           // guard epilogue LDS reuse

    // ---- epilogue: bias, LN, GELU, xbf store, fused gate ----
    u32* Af0 = AfA;
    float2* red  = (float2*)Af0;           // 128 float2 (w*32+rl)
    float*  muv  = (float*)(Af0 + 256);    // 32
    float*  rsv  = (float*)(Af0 + 288);    // 32
    float*  gred = (float*)(Af0 + 512);    // 512: [w][rl][e]
    float*  sacc = (float*)(Af0 + 1024);   // 8

    float bv[4], gvv[4], blv[4]; float4 wgv[4];
#pragma unroll
    for (int nt = 0; nt < 4; ++nt) {
        int col = w * 64 + nt * 16 + l16;
        bv[nt] = bfv_[col]; gvv[nt] = gf[col]; blv[nt] = bfln[col];
        wgv[nt] = *(const float4*)(Wg + col * 4);
    }
    if (tid < 8) sacc[tid] = 0.f;
#pragma unroll
    for (int mt = 0; mt < 2; ++mt)
#pragma unroll
        for (int r = 0; r < 4; ++r) {
            float ss = 0.f, qq = 0.f;
#pragma unroll
            for (int nt = 0; nt < 4; ++nt) {
                float v = acc[mt][nt][r] + bv[nt];
                acc[mt][nt][r] = v;
                ss += v; qq += v * v;
            }
#pragma unroll
            for (int d = 1; d < 16; d <<= 1) { ss += __shfl_xor(ss, d); qq += __shfl_xor(qq, d); }
            if (l16 == 0) red[w * 32 + mt * 16 + quad * 4 + r] = make_float2(ss, qq);
        }
    __syncthreads();
    if (tid < 32) {
        float ss = 0.f, qq = 0.f;
#pragma unroll
        for (int ww = 0; ww < 4; ++ww) { float2 t = red[ww * 32 + tid]; ss += t.x; qq += t.y; }
        float mu = ss * (1.f / 256.f);
        float var = qq * (1.f / 256.f) - mu * mu;
        muv[tid] = mu;
        rsv[tid] = 1.f / sqrtf(var + 1e-5f);
    }
    __syncthreads();
#pragma unroll
    for (int mt = 0; mt < 2; ++mt)
#pragma unroll
        for (int r = 0; r < 4; ++r) {
            int rl = mt * 16 + quad * 4 + r;
            float mu = muv[rl], rs = rsv[rl];
#pragma unroll
            for (int nt = 0; nt < 4; ++nt) {
                int col = w * 64 + nt * 16 + l16;
                float t = (acc[mt][nt][r] - mu) * rs * gvv[nt] + blv[nt];
                float g = gelu_exact(t);
                acc[mt][nt][r] = g;
                xbf[(size_t)(m0 + rl) * 256 + col] = f2bf(g);
            }
        }
    // gate partials (fp32 x, pre-bf16-truncation)
#pragma unroll
    for (int mt = 0; mt < 2; ++mt)
#pragma unroll
        for (int r = 0; r < 4; ++r) {
            int rl = mt * 16 + quad * 4 + r;
            float p0 = 0.f, p1 = 0.f, p2 = 0.f, p3 = 0.f;
#pragma unroll
            for (int nt = 0; nt < 4; ++nt) {
                float g = acc[mt][nt][r];
                p0 += g * wgv[nt].x; p1 += g * wgv[nt].y;
                p2 += g * wgv[nt].z; p3 += g * wgv[nt].w;
            }
#pragma unroll
            for (int d = 1; d < 16; d <<= 1) {
                p0 += __shfl_xor(p0, d); p1 += __shfl_xor(p1, d);
                p2 += __shfl_xor(p2, d); p3 += __shfl_xor(p3, d);
            }
            if (l16 == 0) {
                float* gp = gred + w * 128 + rl * 4;
                gp[0] = p0; gp[1] = p1; gp[2] = p2; gp[3] = p3;
            }
        }
    __syncthreads();
    if (tid < 32) {
        int row = tid;
        float lg[4];
#pragma unroll
        for (int e = 0; e < 4; ++e)
            lg[e] = gred[row * 4 + e] + gred[128 + row * 4 + e] +
                    gred[256 + row * 4 + e] + gred[384 + row * 4 + e];
        float mx = fmaxf(fmaxf(lg[0], lg[1]), fmaxf(lg[2], lg[3]));
        float ex[4]; float Z = 0.f;
#pragma unroll
        for (int e = 0; e < 4; ++e) { ex[e] = expf(lg[e] - mx); Z += ex[e]; }
        int i0 = 0; float v0 = lg[0];
#pragma unroll
        for (int e = 1; e < 4; ++e) if (lg[e] > v0) { v0 = lg[e]; i0 = e; }
        int i1 = -1; float v1 = -1e30f;
#pragma unroll
        for (int e = 0; e < 4; ++e) if (e != i0 && lg[e] > v1) { v1 = lg[e]; i1 = e; }
        float t = expf(v1 - v0);
        float wA = 1.f / (1.f + t), wB = t / (1.f + t);
        float w4[4] = {0.f, 0.f, 0.f, 0.f};
        w4[i0] = wA; w4[i1] = wB;
#pragma unroll
        for (int e = 0; e < 4; ++e) wr[(size_t)(m0 + row) * 4 + e] = w4[e];
#pragma unroll
        for (int e = 0; e < 4; ++e) atomicAdd(&sacc[e], ex[e] / Z);
        atomicAdd(&sacc[4 + i0], 1.f);
        atomicAdd(&sacc[4 + i1], 1.f);
    }
    __syncthreads();
    if (tid < 8) atomicAdd(lbacc + tid, sacc[tid]);
}

// ---------------------------------------------------------------------------
// K2: expert GEMM + bias + GELU, batched over blockIdx.z = expert.
// Cross-barrier prefetch, 10 loads/stage. kiters is even (4 or 8).
// ---------------------------------------------------------------------------
__global__ __launch_bounds__(256) void expert_gemm_kernel(
    const u16* __restrict__ A, int lda, size_t aE,
    const u16* __restrict__ BT, size_t bE,
    const float* __restrict__ bias, int biasE,
    u16* __restrict__ outp, int ldo, size_t oE) {
    __shared__ __align__(16) u16 AsA[4096];
    __shared__ __align__(16) u16 AsB[4096];
    __shared__ __align__(16) u16 BsA[16384];
    __shared__ __align__(16) u16 BsB[16384];
    int tid = threadIdx.x;
    int w = tid >> 6, lane = tid & 63, quad = lane >> 4, l16 = lane & 15;
    int m0 = blockIdx.x * 64;
    int col0 = blockIdx.y * 256;
    int e = blockIdx.z;
    f32x4 acc[4][4] = {};
    const u16* Ag = A + e * aE + (size_t)m0 * lda;
    const u16* Bg = BT + e * bE + (size_t)col0 * lda;
    int kiters = lda >> 6;
    stageA64(Ag, lda, AsA, tid);
    stageB64(Bg, lda, BsA, tid);
    for (int kit = 0; kit < kiters; kit += 2) {
        stageA64(Ag + (kit + 1) * 64, lda, AsB, tid);
        stageB64(Bg + (kit + 1) * 64, lda, BsB, tid);
        WAIT_VM(10);
        BARRIER();
        compute64(AsA, BsA, acc, w, l16, quad);
        LGKBAR();
        if (kit + 2 < kiters) {
            stageA64(Ag + (kit + 2) * 64, lda, AsA, tid);
            stageB64(Bg + (kit + 2) * 64, lda, BsA, tid);
            WAIT_VM(10);
        } else {
            WAIT_VM(0);
        }
        BARRIER();
        compute64(AsB, BsB, acc, w, l16, quad);
        LGKBAR();
    }
#pragma unroll
    for (int nt = 0; nt < 4; ++nt) {
        int col = col0 + w * 64 + nt * 16 + l16;
        float bvv = bias[e * biasE + col];
#pragma unroll
        for (int mt = 0; mt < 4; ++mt)
#pragma unroll
            for (int r = 0; r < 4; ++r) {
                int row = m0 + mt * 16 + quad * 4 + r;
                outp[e * oE + (size_t)row * ldo + col] = f2bf(gelu_exact(acc[mt][nt][r] + bvv));
            }
    }
}

// ---------------------------------------------------------------------------
// K3: combine — 32-row tiles; cross-barrier prefetch over all 16 (e,kit)
// steps; x in regs; per-expert LN epilogue under lgkm-only barriers.
// ---------------------------------------------------------------------------
__global__ __launch_bounds__(256) void combine_kernel(
    const u16* __restrict__ h2, const u16* __restrict__ W3T,
    const float* __restrict__ b3, const float* __restrict__ eg, const float* __restrict__ eb,
    const u16* __restrict__ xbf, const float* __restrict__ wr,
    const float* __restrict__ lbacc, float* __restrict__ outp) {
    __shared__ __align__(16) u16 AsA[2048];     // 4KB: 32 rows x 64 k
    __shared__ __align__(16) u16 AsB[2048];
    __shared__ __align__(16) u16 BsA[16384];    // 32KB
    __shared__ __align__(16) u16 BsB[16384];
    __shared__ float wl[128];
    __shared__ float2 red[128];
    __shared__ float muv[32], rsv[32];
    int tid = threadIdx.x;
    int w = tid >> 6, lane = tid & 63, quad = lane >> 4, l16 = lane & 15;
    int m0 = blockIdx.x * 32;
    if (blockIdx.x == 0 && tid == 0) {          // lb_loss (lbacc complete: fusion done)
        float lb = 0.f;
#pragma unroll
        for (int e = 0; e < 4; ++e)
            lb += (lbacc[4 + e] / 32768.f) * (lbacc[e] / 16384.f);
        outp[4194304] = 4.f * lb;
    }
    // ---- x tile -> registers (bounce through BsA, then BsA reused) ----
    u16* xs = BsA;
#pragma unroll
    for (int i = 0; i < 4; ++i) {
        int s = i * 256 + tid;
        *(uint4*)(xs + s * 8) = *(const uint4*)(xbf + (size_t)m0 * 256 + s * 8);
    }
    if (tid < 128) wl[tid] = wr[(size_t)m0 * 4 + tid];
    __syncthreads();
    float xr[2][4][4];
#pragma unroll
    for (int mt = 0; mt < 2; ++mt)
#pragma unroll
        for (int r = 0; r < 4; ++r) {
            int rl = mt * 16 + quad * 4 + r;
#pragma unroll
            for (int nt = 0; nt < 4; ++nt) {
                int col = w * 64 + nt * 16 + l16;
                xr[mt][r][nt] = bf2f(xs[rl * 256 + col]);
            }
        }
    __syncthreads();                            // x reads done; BsA free

    f32x4 oacc[2][4] = {};
    f32x4 acc[2][4] = {};
    auto stageP = [&](u16* As, u16* Bs, int p) {  // p = e*4 + kit; 9 loads
        int ee = p >> 2, kit = p & 3;
        stageA64_R32(h2 + ((size_t)ee * 16384 + m0) * 256 + kit * 64, 256, As, tid);
        stageB64(W3T + (size_t)ee * 65536 + kit * 64, 256, Bs, tid);
    };
    auto epilogue = [&](int e) {
        float b3v[4], egv[4], ebv[4];
#pragma unroll
        for (int nt = 0; nt < 4; ++nt) {
            int col = w * 64 + nt * 16 + l16;
            b3v[nt] = b3[e * 256 + col]; egv[nt] = eg[e * 256 + col]; ebv[nt] = eb[e * 256 + col];
        }
#pragma unroll
        for (int mt = 0; mt < 2; ++mt)
#pragma unroll
            for (int r = 0; r < 4; ++r) {
                int rl = mt * 16 + quad * 4 + r;
                float ss = 0.f, qq = 0.f;
#pragma unroll
                for (int nt = 0; nt < 4; ++nt) {
                    float v = acc[mt][nt][r] + b3v[nt] + xr[mt][r][nt];
                    acc[mt][nt][r] = v;
                    ss += v; qq += v * v;
                }
#pragma unroll
                for (int d = 1; d < 16; d <<= 1) { ss += __shfl_xor(ss, d); qq += __shfl_xor(qq, d); }
                if (l16 == 0) red[w * 32 + rl] = make_float2(ss, qq);
            }
        LGKBAR();                               // keep next-step prefetch in flight
        if (tid < 32) {
            float ss = 0.f, qq = 0.f;
#pragma unroll
            for (int ww = 0; ww < 4; ++ww) { float2 t = red[ww * 32 + tid]; ss += t.x; qq += t.y; }
            float mu = ss * (1.f / 256.f);
            float var = qq * (1.f / 256.f) - mu * mu;
            muv[tid] = mu;
            rsv[tid] = 1.f / sqrtf(var + 1e-5f);
        }
        LGKBAR();
#pragma unroll
        for (int mt = 0; mt < 2; ++mt)
#pragma unroll
            for (int r = 0; r < 4; ++r) {
                int rl = mt * 16 + quad * 4 + r;
                float mu = muv[rl], rs = rsv[rl], we = wl[rl * 4 + e];
#pragma unroll
                for (int nt = 0; nt < 4; ++nt) {
                    float y = (acc[mt][nt][r] - mu) * rs * egv[nt] + ebv[nt];
                    oacc[mt][nt][r] += we * y;
                    acc[mt][nt][r] = 0.f;       // reset for next expert
                }
            }
    };

    stageP(AsA, BsA, 0);                        // 9 in flight
    for (int p = 0; p < 16; p += 2) {
        stageP(AsB, BsB, p + 1);                // 18 in flight
        WAIT_VM(9);                             // A ready, B stays in flight
        BARRIER();
        compute64_R32(AsA, BsA, acc, w, l16, quad);
        LGKBAR();
        if (p + 2 < 16) { stageP(AsA, BsA, p + 2); WAIT_VM(9); }
        else            { WAIT_VM(0); }
        BARRIER();
        compute64_R32(AsB, BsB, acc, w, l16, quad);
        LGKBAR();
        if ((p & 3) == 2) epilogue(p >> 2);     // experts finish at steps 3,7,11,15
    }
#pragma unroll
    for (int mt = 0; mt < 2; ++mt)
#pragma unroll
        for (int r = 0; r < 4; ++r) {
            int rl = mt * 16 + quad * 4 + r;
#pragma unroll
            for (int nt = 0; nt < 4; ++nt) {
                int col = w * 64 + nt * 16 + l16;
                outp[(size_t)(m0 + rl) * 256 + col] = oacc[mt][nt][r];
            }
        }
}

// ---------------------------------------------------------------------------
extern "C" void kernel_launch(void* const* d_in, const int* in_sizes, int n_in,
                              void* d_out, int out_size, void* d_ws, size_t ws_size,
                              hipStream_t stream) {
    const float* vis   = (const float*)d_in[0];
    const float* lang  = (const float*)d_in[1];
    const float* state = (const float*)d_in[2];
    const float* Wf    = (const float*)d_in[3];
    const float* bf_   = (const float*)d_in[4];
    const float* gf    = (const float*)d_in[5];
    const float* bfln  = (const float*)d_in[6];
    const float* Wg    = (const float*)d_in[7];
    const float* W1    = (const float*)d_in[8];
    const float* b1    = (const float*)d_in[9];
    const float* W2    = (const float*)d_in[10];
    const float* b2    = (const float*)d_in[11];
    const float* W3    = (const float*)d_in[12];
    const float* b3    = (const float*)d_in[13];
    const float* eg    = (const float*)d_in[14];
    const float* eb    = (const float*)d_in[15];
    float* outp = (float*)d_out;

    char* ws = (char*)d_ws;
    size_t off = 0;
    float* lbacc = (float*)(ws + off); off += 256;
    u16* WFT  = (u16*)(ws + off); off += 819200UL;     // WfT [256][1600]
    u16* W1T  = (u16*)(ws + off); off += 1048576UL;    // [E][512][256]
    u16* W2T  = (u16*)(ws + off); off += 1048576UL;    // [E][256][512]
    u16* W3T  = (u16*)(ws + off); off += 524288UL;     // [E][256][256]
    u16* XBF  = (u16*)(ws + off); off += 8388608UL;    // x bf16 [B][256]
    float* WR = (float*)(ws + off); off += 262144UL;   // gate weights [B][4]
    u16* H1   = (u16*)(ws + off); off += 67108864UL;   // [E][B][512]
    u16* H2   = (u16*)(ws + off); off += 33554432UL;   // [E][B][256]
    if (ws_size < off) return;

    int prep_blocks = (PREP_ITEMS + 255) / 256;
    prep_kernel<<<prep_blocks, 256, 0, stream>>>(Wf, W1, W2, W3, WFT, W1T, W2T, W3T, lbacc);
    fusion_kernel<<<512, 256, 0, stream>>>(vis, lang, state, WFT, bf_, gf, bfln, Wg,
                                           XBF, WR, lbacc);
    expert_gemm_kernel<<<dim3(256, 2, 4), 256, 0, stream>>>(
        XBF, 256, 0, W1T, 131072, b1, 512, H1, 512, 8388608UL);
    expert_gemm_kernel<<<dim3(256, 1, 4), 256, 0, stream>>>(
        H1, 512, 8388608UL, W2T, 131072, b2, 256, H2, 256, 4194304UL);
    combine_kernel<<<512, 256, 0, stream>>>(H2, W3T, b3, eg, eb, XBF, WR, lbacc, outp);
}

// Round 4
// 338.345 us; speedup vs baseline: 1.0517x; 1.0121x over previous
//
#include <hip/hip_runtime.h>
#include <math.h>

// ---------------------------------------------------------------------------
// FusionMoE R6: occupancy attack. fusion+combine move to 512-thread blocks
// (8 waves, same 32x256 tiles, single-buffer LDS, plain R2 schedule) ->
// 16 waves/CU instead of 8 (grids are 512 = 2 blocks/CU, previously 4-wave).
// expert_gemm reverted to the measured-best R2 form (256t, single-buffer,
// 4 blocks/CU). Pipelining experiments (R3-R5) showed zero effect on fusion:
// it is concurrency-bound, not stage-latency-bound. Math identical to R2.
// ---------------------------------------------------------------------------

typedef unsigned short u16;
typedef unsigned int u32;
typedef __attribute__((ext_vector_type(8))) short bf16x8;
typedef __attribute__((ext_vector_type(4))) float f32x4;

__device__ __forceinline__ float bf2f(u16 u) {
    union { u32 i; float f; } v; v.i = ((u32)u) << 16; return v.f;
}
__device__ __forceinline__ u16 f2bf(float f) {  // RNE
    union { float f; u32 i; } v; v.f = f;
    u32 x = v.i;
    return (u16)((x + 0x7fffu + ((x >> 16) & 1u)) >> 16);
}
__device__ __forceinline__ float gelu_exact(float v) {
    return 0.5f * v * (1.0f + erff(v * 0.70710678118654752f));
}

typedef __attribute__((address_space(1))) void GV;
typedef __attribute__((address_space(3))) void SV;
__device__ __forceinline__ void gldlds(const void* g, void* l) {
    __builtin_amdgcn_global_load_lds((GV*)g, (SV*)l, 16, 0, 0);
}

// pack two f32 (bit-truncate) into one u32 of two bf16 (f0 low, f1 high)
__device__ __forceinline__ u32 pk2(u32 f0, u32 f1) {
    return __builtin_amdgcn_perm(f1, f0, 0x07060302);
}

// ----- bf16 staging helpers (XOR-8 swizzle), verified in R1 -----
// 256-thread variants (expert_gemm)
__device__ __forceinline__ void stageA64(const u16* Ag, int lda, u16* As, int tid) {
#pragma unroll
    for (int i = 0; i < 2; ++i) {
        int s = i * 256 + tid;          // 512 slots (64 rows x 8 chunks of 16B)
        int m = s >> 3, c = s & 7;
        gldlds(Ag + m * lda + (c ^ (m & 7)) * 8, As + s * 8);
    }
}
__device__ __forceinline__ void stageB64(const u16* Bg, int ldb, u16* Bs, int tid) {
#pragma unroll
    for (int i = 0; i < 8; ++i) {
        int s = i * 256 + tid;          // 2048 slots (256 n-rows x 8 chunks)
        int n = s >> 3, c = s & 7;
        gldlds(Bg + n * ldb + (c ^ (n & 7)) * 8, Bs + s * 8);
    }
}
// 512-thread variants (fusion / combine)
__device__ __forceinline__ void stageA32_512(const u16* Ag, int lda, u16* As, int tid) {
    if (tid < 256) {                    // 256 slots (32 rows x 8 chunks)
        int m = tid >> 3, c = tid & 7;
        gldlds(Ag + m * lda + (c ^ (m & 7)) * 8, As + tid * 8);
    }
}
__device__ __forceinline__ void stageB64_512(const u16* Bg, int ldb, u16* Bs, int tid) {
#pragma unroll
    for (int i = 0; i < 4; ++i) {
        int s = i * 512 + tid;          // 2048 slots (256 n-rows x 8 chunks)
        int n = s >> 3, c = s & 7;
        gldlds(Bg + n * ldb + (c ^ (n & 7)) * 8, Bs + s * 8);
    }
}

// 4-wave 64-row compute (expert_gemm)
__device__ __forceinline__ void compute64(const u16* As, const u16* Bs, f32x4 acc[4][4],
                                          int w, int l16, int quad) {
#pragma unroll
    for (int ks = 0; ks < 2; ++ks) {
        bf16x8 a[4];
#pragma unroll
        for (int mt = 0; mt < 4; ++mt) {
            int m = mt * 16 + l16;
            a[mt] = *(const bf16x8*)(As + m * 64 + (((ks * 4 + quad) ^ (m & 7)) << 3));
        }
#pragma unroll
        for (int nt = 0; nt < 4; ++nt) {
            int n = w * 64 + nt * 16 + l16;
            bf16x8 b = *(const bf16x8*)(Bs + n * 64 + (((ks * 4 + quad) ^ (n & 7)) << 3));
#pragma unroll
            for (int mt = 0; mt < 4; ++mt)
                acc[mt][nt] = __builtin_amdgcn_mfma_f32_16x16x32_bf16(a[mt], b, acc[mt][nt], 0, 0, 0);
        }
    }
}
// 8-wave 32-row compute (combine): each wave covers 32 cols (nt<2)
__device__ __forceinline__ void compute32_8w(const u16* As, const u16* Bs, f32x4 acc[2][2],
                                             int w, int l16, int quad) {
#pragma unroll
    for (int ks = 0; ks < 2; ++ks) {
        bf16x8 a[2];
#pragma unroll
        for (int mt = 0; mt < 2; ++mt) {
            int m = mt * 16 + l16;
            a[mt] = *(const bf16x8*)(As + m * 64 + (((ks * 4 + quad) ^ (m & 7)) << 3));
        }
#pragma unroll
        for (int nt = 0; nt < 2; ++nt) {
            int n = w * 32 + nt * 16 + l16;
            bf16x8 b = *(const bf16x8*)(Bs + n * 64 + (((ks * 4 + quad) ^ (n & 7)) << 3));
#pragma unroll
            for (int mt = 0; mt < 2; ++mt)
                acc[mt][nt] = __builtin_amdgcn_mfma_f32_16x16x32_bf16(a[mt], b, acc[mt][nt], 0, 0, 0);
        }
    }
}

// ---------------------------------------------------------------------------
// K0: prep — weight transposes to bf16 + lbacc zero (weights only, ~7 MB)
// ---------------------------------------------------------------------------
#define SEG_WF  409600
#define SEG_W1  524288
#define SEG_W2  524288
#define SEG_W3  262144
#define PREP_ITEMS (SEG_WF + SEG_W1 + SEG_W2 + SEG_W3 + 8)

__global__ __launch_bounds__(256) void prep_kernel(
    const float* __restrict__ Wf, const float* __restrict__ W1, const float* __restrict__ W2,
    const float* __restrict__ W3,
    u16* __restrict__ wft, u16* __restrict__ w1t, u16* __restrict__ w2t, u16* __restrict__ w3t,
    float* __restrict__ lbacc) {
    int idx = blockIdx.x * 256 + threadIdx.x;
    if (idx < SEG_WF) {  // WfT[n<256][k<1600] = Wf[k][n]
        int n = idx / 1600, k = idx % 1600;
        wft[idx] = f2bf(Wf[(size_t)k * 256 + n]);
        return;
    }
    idx -= SEG_WF;
    if (idx < SEG_W1) {  // W1T[e][n<512][k<256] = W1[e][k][n]
        int e = idx >> 17, r = idx & 131071;
        int n = r >> 8, k = r & 255;
        w1t[idx] = f2bf(W1[(size_t)e * 131072 + (size_t)k * 512 + n]);
        return;
    }
    idx -= SEG_W1;
    if (idx < SEG_W2) {  // W2T[e][n<256][k<512] = W2[e][k][n]
        int e = idx >> 17, r = idx & 131071;
        int n = r >> 9, k = r & 511;
        w2t[idx] = f2bf(W2[(size_t)e * 131072 + (size_t)k * 256 + n]);
        return;
    }
    idx -= SEG_W2;
    if (idx < SEG_W3) {  // W3T[e][n<256][k<256] = W3[e][k][n]
        int e = idx >> 16, r = idx & 65535;
        int n = r >> 8, k = r & 255;
        w3t[idx] = f2bf(W3[(size_t)e * 65536 + (size_t)k * 256 + n]);
        return;
    }
    idx -= SEG_W3;
    if (idx < 8) lbacc[idx] = 0.0f;
}

// ---------------------------------------------------------------------------
// K1: fusion — 512 threads (8 waves), fp32 A direct, bf16 B, 32x256 tile,
// single-buffer R2 schedule. Epilogue: bias+LN+GELU -> xbf, fused gate.
// ---------------------------------------------------------------------------
__global__ __launch_bounds__(512, 4) void fusion_kernel(
    const float* __restrict__ vis, const float* __restrict__ lang, const float* __restrict__ state,
    const u16* __restrict__ BT, const float* __restrict__ bfv_, const float* __restrict__ gf,
    const float* __restrict__ bfln, const float* __restrict__ Wg,
    u16* __restrict__ xbf, float* __restrict__ wr, float* __restrict__ lbacc) {
    __shared__ __align__(16) u32 Af[2048];   // 8KB: 32 rows x 16 f32-chunks (XOR-16)
    __shared__ __align__(16) u16 Bs[16384];  // 32KB: 256 n x 64 k bf16
    int tid = threadIdx.x;
    int w = tid >> 6, lane = tid & 63, quad = lane >> 4, l16 = lane & 15;
    int m0 = blockIdx.x * 32;
    f32x4 acc[2][2] = {};

    for (int kit = 0; kit < 25; ++kit) {
        const float* base; int ld;
        if (kit < 12)      { base = vis   + (size_t)m0 * 768 + kit * 64;        ld = 768; }
        else if (kit < 24) { base = lang  + (size_t)m0 * 768 + (kit - 12) * 64; ld = 768; }
        else               { base = state + (size_t)m0 * 64;                    ld = 64; }
        {   // A: 512 slots of 16B (4 f32), 1 per thread
            int s = tid;
            int m = s >> 4, c = s & 15;
            gldlds(base + m * ld + (c ^ (m & 15)) * 4, Af + s * 4);
        }
        stageB64_512(BT + kit * 64, 1600, Bs, tid);   // 4 loads/thread
        __syncthreads();
#pragma unroll
        for (int ks = 0; ks < 2; ++ks) {
            bf16x8 a[2];
#pragma unroll
            for (int mt = 0; mt < 2; ++mt) {
                int m = mt * 16 + l16;
                int c0 = ks * 8 + quad * 2;
                const u32* rowp = Af + m * 64;
                uint4 f0 = *(const uint4*)(rowp + (c0 ^ (m & 15)) * 4);
                uint4 f1 = *(const uint4*)(rowp + ((c0 + 1) ^ (m & 15)) * 4);
                union { u32 u[4]; bf16x8 v; } pk;
                pk.u[0] = pk2(f0.x, f0.y); pk.u[1] = pk2(f0.z, f0.w);
                pk.u[2] = pk2(f1.x, f1.y); pk.u[3] = pk2(f1.z, f1.w);
                a[mt] = pk.v;
            }
#pragma unroll
            for (int nt = 0; nt < 2; ++nt) {
                int n = w * 32 + nt * 16 + l16;
                bf16x8 b = *(const bf16x8*)(Bs + n * 64 + (((ks * 4 + quad) ^ (n & 7)) << 3));
#pragma unroll
                for (int mt = 0; mt < 2; ++mt)
                    acc[mt][nt] = __builtin_amdgcn_mfma_f32_16x16x32_bf16(a[mt], b, acc[mt][nt], 0, 0, 0);
            }
        }
        __syncthreads();
    }

    // ---- epilogue: bias, LN, GELU, xbf store, fused gate ----
    float2* red  = (float2*)Af;            // 256 float2 (w*32+rl)  Af[0..511]
    float*  muv  = (float*)(Af + 512);     // 32
    float*  rsv  = (float*)(Af + 544);     // 32
    float*  gred = (float*)(Af + 576);     // 1024: [w][rl][e]      Af[576..1599]
    float*  sacc = (float*)(Af + 1600);    // 8

    float bv[2], gvv[2], blv[2]; float4 wgv[2];
#pragma unroll
    for (int nt = 0; nt < 2; ++nt) {
        int col = w * 32 + nt * 16 + l16;
        bv[nt] = bfv_[col]; gvv[nt] = gf[col]; blv[nt] = bfln[col];
        wgv[nt] = *(const float4*)(Wg + col * 4);
    }
    if (tid < 8) sacc[tid] = 0.f;
#pragma unroll
    for (int mt = 0; mt < 2; ++mt)
#pragma unroll
        for (int r = 0; r < 4; ++r) {
            float ss = 0.f, qq = 0.f;
#pragma unroll
            for (int nt = 0; nt < 2; ++nt) {
                float v = acc[mt][nt][r] + bv[nt];
                acc[mt][nt][r] = v;
                ss += v; qq += v * v;
            }
#pragma unroll
            for (int d = 1; d < 16; d <<= 1) { ss += __shfl_xor(ss, d); qq += __shfl_xor(qq, d); }
            if (l16 == 0) red[w * 32 + mt * 16 + quad * 4 + r] = make_float2(ss, qq);
        }
    __syncthreads();
    if (tid < 32) {
        float ss = 0.f, qq = 0.f;
#pragma unroll
        for (int ww = 0; ww < 8; ++ww) { float2 t = red[ww * 32 + tid]; ss += t.x; qq += t.y; }
        float mu = ss * (1.f / 256.f);
        float var = qq * (1.f / 256.f) - mu * mu;
        muv[tid] = mu;
        rsv[tid] = 1.f / sqrtf(var + 1e-5f);
    }
    __syncthreads();
#pragma unroll
    for (int mt = 0; mt < 2; ++mt)
#pragma unroll
        for (int r = 0; r < 4; ++r) {
            int rl = mt * 16 + quad * 4 + r;
            float mu = muv[rl], rs = rsv[rl];
#pragma unroll
            for (int nt = 0; nt < 2; ++nt) {
                int col = w * 32 + nt * 16 + l16;
                float t = (acc[mt][nt][r] - mu) * rs * gvv[nt] + blv[nt];
                float g = gelu_exact(t);
                acc[mt][nt][r] = g;
                xbf[(size_t)(m0 + rl) * 256 + col] = f2bf(g);
            }
        }
    // gate partials (fp32 x, pre-bf16-truncation)
#pragma unroll
    for (int mt = 0; mt < 2; ++mt)
#pragma unroll
        for (int r = 0; r < 4; ++r) {
            int rl = mt * 16 + quad * 4 + r;
            float p0 = 0.f, p1 = 0.f, p2 = 0.f, p3 = 0.f;
#pragma unroll
            for (int nt = 0; nt < 2; ++nt) {
                float g = acc[mt][nt][r];
                p0 += g * wgv[nt].x; p1 += g * wgv[nt].y;
                p2 += g * wgv[nt].z; p3 += g * wgv[nt].w;
            }
#pragma unroll
            for (int d = 1; d < 16; d <<= 1) {
                p0 += __shfl_xor(p0, d); p1 += __shfl_xor(p1, d);
                p2 += __shfl_xor(p2, d); p3 += __shfl_xor(p3, d);
            }
            if (l16 == 0) {
                float* gp = gred + w * 128 + rl * 4;
                gp[0] = p0; gp[1] = p1; gp[2] = p2; gp[3] = p3;
            }
        }
    __syncthreads();
    if (tid < 32) {
        int row = tid;
        float lg[4];
#pragma unroll
        for (int e = 0; e < 4; ++e) {
            float s = 0.f;
#pragma unroll
            for (int ww = 0; ww < 8; ++ww) s += gred[ww * 128 + row * 4 + e];
            lg[e] = s;
        }
        float mx = fmaxf(fmaxf(lg[0], lg[1]), fmaxf(lg[2], lg[3]));
        float ex[4]; float Z = 0.f;
#pragma unroll
        for (int e = 0; e < 4; ++e) { ex[e] = expf(lg[e] - mx); Z += ex[e]; }
        int i0 = 0; float v0 = lg[0];
#pragma unroll
        for (int e = 1; e < 4; ++e) if (lg[e] > v0) { v0 = lg[e]; i0 = e; }
        int i1 = -1; float v1 = -1e30f;
#pragma unroll
        for (int e = 0; e < 4; ++e) if (e != i0 && lg[e] > v1) { v1 = lg[e]; i1 = e; }
        float t = expf(v1 - v0);
        float wA = 1.f / (1.f + t), wB = t / (1.f + t);
        float w4[4] = {0.f, 0.f, 0.f, 0.f};
        w4[i0] = wA; w4[i1] = wB;
#pragma unroll
        for (int e = 0; e < 4; ++e) wr[(size_t)(m0 + row) * 4 + e] = w4[e];
#pragma unroll
        for (int e = 0; e < 4; ++e) atomicAdd(&sacc[e], ex[e] / Z);
        atomicAdd(&sacc[4 + i0], 1.f);
        atomicAdd(&sacc[4 + i1], 1.f);
    }
    __syncthreads();
    if (tid < 8) atomicAdd(lbacc + tid, sacc[tid]);
}

// ---------------------------------------------------------------------------
// K2: expert GEMM + bias + GELU, batched over blockIdx.z = expert.
// R2 form: 256t, single-buffer, 40KB LDS -> 4 blocks/CU.
// ---------------------------------------------------------------------------
__global__ __launch_bounds__(256) void expert_gemm_kernel(
    const u16* __restrict__ A, int lda, size_t aE,
    const u16* __restrict__ BT, size_t bE,
    const float* __restrict__ bias, int biasE,
    u16* __restrict__ outp, int ldo, size_t oE) {
    __shared__ __align__(16) u16 As[4096];
    __shared__ __align__(16) u16 Bs[16384];
    int tid = threadIdx.x;
    int w = tid >> 6, lane = tid & 63, quad = lane >> 4, l16 = lane & 15;
    int m0 = blockIdx.x * 64;
    int col0 = blockIdx.y * 256;
    int e = blockIdx.z;
    f32x4 acc[4][4] = {};
    const u16* Ag = A + e * aE + (size_t)m0 * lda;
    const u16* Bg = BT + e * bE + (size_t)col0 * lda;
    int kiters = lda >> 6;
    for (int kit = 0; kit < kiters; ++kit) {
        stageA64(Ag + kit * 64, lda, As, tid);
        stageB64(Bg + kit * 64, lda, Bs, tid);
        __syncthreads();
        compute64(As, Bs, acc, w, l16, quad);
        __syncthreads();
    }
#pragma unroll
    for (int nt = 0; nt < 4; ++nt) {
        int col = col0 + w * 64 + nt * 16 + l16;
        float bvv = bias[e * biasE + col];
#pragma unroll
        for (int mt = 0; mt < 4; ++mt)
#pragma unroll
            for (int r = 0; r < 4; ++r) {
                int row = m0 + mt * 16 + quad * 4 + r;
                outp[e * oE + (size_t)row * ldo + col] = f2bf(gelu_exact(acc[mt][nt][r] + bvv));
            }
    }
}

// ---------------------------------------------------------------------------
// K3: combine — 512 threads (8 waves), 32-row tiles, single-buffer.
// h2@W3 + b3 + x -> LN -> *eg+eb, out += w[row][e]*y; lb by block 0.
// ---------------------------------------------------------------------------
__global__ __launch_bounds__(512, 4) void combine_kernel(
    const u16* __restrict__ h2, const u16* __restrict__ W3T,
    const float* __restrict__ b3, const float* __restrict__ eg, const float* __restrict__ eb,
    const u16* __restrict__ xbf, const float* __restrict__ wr,
    const float* __restrict__ lbacc, float* __restrict__ outp) {
    __shared__ __align__(16) u16 As[2048];      // 4KB: 32 rows x 64 k
    __shared__ __align__(16) u16 Bs[16384];     // 32KB
    __shared__ float wl[128];
    __shared__ float2 red[256];
    __shared__ float muv[32], rsv[32];
    int tid = threadIdx.x;
    int w = tid >> 6, lane = tid & 63, quad = lane >> 4, l16 = lane & 15;
    int m0 = blockIdx.x * 32;
    if (blockIdx.x == 0 && tid == 0) {          // lb_loss (lbacc complete: fusion done)
        float lb = 0.f;
#pragma unroll
        for (int e = 0; e < 4; ++e)
            lb += (lbacc[4 + e] / 32768.f) * (lbacc[e] / 16384.f);
        outp[4194304] = 4.f * lb;
    }
    // ---- x tile -> registers (bounce through Bs, then Bs reused) ----
#pragma unroll
    for (int i = 0; i < 2; ++i) {
        int s = i * 512 + tid;                  // 1024 slots of 16B = 32x256 bf16
        *(uint4*)(Bs + s * 8) = *(const uint4*)(xbf + (size_t)m0 * 256 + s * 8);
    }
    if (tid < 128) wl[tid] = wr[(size_t)m0 * 4 + tid];
    __syncthreads();
    float xr[2][4][2];
#pragma unroll
    for (int mt = 0; mt < 2; ++mt)
#pragma unroll
        for (int r = 0; r < 4; ++r) {
            int rl = mt * 16 + quad * 4 + r;
#pragma unroll
            for (int nt = 0; nt < 2; ++nt) {
                int col = w * 32 + nt * 16 + l16;
                xr[mt][r][nt] = bf2f(Bs[rl * 256 + col]);
            }
        }
    __syncthreads();                            // x reads done; Bs free

    f32x4 oacc[2][2] = {};
    for (int e = 0; e < 4; ++e) {
        f32x4 acc[2][2] = {};
        const u16* Ag = h2 + ((size_t)e * 16384 + m0) * 256;
        const u16* Bg = W3T + (size_t)e * 65536;
        for (int kit = 0; kit < 4; ++kit) {
            stageA32_512(Ag + kit * 64, 256, As, tid);
            stageB64_512(Bg + kit * 64, 256, Bs, tid);
            __syncthreads();
            compute32_8w(As, Bs, acc, w, l16, quad);
            __syncthreads();
        }
        float b3v[2], egv[2], ebv[2];
#pragma unroll
        for (int nt = 0; nt < 2; ++nt) {
            int col = w * 32 + nt * 16 + l16;
            b3v[nt] = b3[e * 256 + col]; egv[nt] = eg[e * 256 + col]; ebv[nt] = eb[e * 256 + col];
        }
#pragma unroll
        for (int mt = 0; mt < 2; ++mt)
#pragma unroll
            for (int r = 0; r < 4; ++r) {
                int rl = mt * 16 + quad * 4 + r;
                float ss = 0.f, qq = 0.f;
#pragma unroll
                for (int nt = 0; nt < 2; ++nt) {
                    float v = acc[mt][nt][r] + b3v[nt] + xr[mt][r][nt];
                    acc[mt][nt][r] = v;
                    ss += v; qq += v * v;
                }
#pragma unroll
                for (int d = 1; d < 16; d <<= 1) { ss += __shfl_xor(ss, d); qq += __shfl_xor(qq, d); }
                if (l16 == 0) red[w * 32 + rl] = make_float2(ss, qq);
            }
        __syncthreads();
        if (tid < 32) {
            float ss = 0.f, qq = 0.f;
#pragma unroll
            for (int ww = 0; ww < 8; ++ww) { float2 t = red[ww * 32 + tid]; ss += t.x; qq += t.y; }
            float mu = ss * (1.f / 256.f);
            float var = qq * (1.f / 256.f) - mu * mu;
            muv[tid] = mu;
            rsv[tid] = 1.f / sqrtf(var + 1e-5f);
        }
        __syncthreads();
#pragma unroll
        for (int mt = 0; mt < 2; ++mt)
#pragma unroll
            for (int r = 0; r < 4; ++r) {
                int rl = mt * 16 + quad * 4 + r;
                float mu = muv[rl], rs = rsv[rl], we = wl[rl * 4 + e];
#pragma unroll
                for (int nt = 0; nt < 2; ++nt) {
                    float y = (acc[mt][nt][r] - mu) * rs * egv[nt] + ebv[nt];
                    oacc[mt][nt][r] += we * y;
                }
            }
    }
#pragma unroll
    for (int mt = 0; mt < 2; ++mt)
#pragma unroll
        for (int r = 0; r < 4; ++r) {
            int rl = mt * 16 + quad * 4 + r;
#pragma unroll
            for (int nt = 0; nt < 2; ++nt) {
                int col = w * 32 + nt * 16 + l16;
                outp[(size_t)(m0 + rl) * 256 + col] = oacc[mt][nt][r];
            }
        }
}

// ---------------------------------------------------------------------------
extern "C" void kernel_launch(void* const* d_in, const int* in_sizes, int n_in,
                              void* d_out, int out_size, void* d_ws, size_t ws_size,
                              hipStream_t stream) {
    const float* vis   = (const float*)d_in[0];
    const float* lang  = (const float*)d_in[1];
    const float* state = (const float*)d_in[2];
    const float* Wf    = (const float*)d_in[3];
    const float* bf_   = (const float*)d_in[4];
    const float* gf    = (const float*)d_in[5];
    const float* bfln  = (const float*)d_in[6];
    const float* Wg    = (const float*)d_in[7];
    const float* W1    = (const float*)d_in[8];
    const float* b1    = (const float*)d_in[9];
    const float* W2    = (const float*)d_in[10];
    const float* b2    = (const float*)d_in[11];
    const float* W3    = (const float*)d_in[12];
    const float* b3    = (const float*)d_in[13];
    const float* eg    = (const float*)d_in[14];
    const float* eb    = (const float*)d_in[15];
    float* outp = (float*)d_out;

    char* ws = (char*)d_ws;
    size_t off = 0;
    float* lbacc = (float*)(ws + off); off += 256;
    u16* WFT  = (u16*)(ws + off); off += 819200UL;     // WfT [256][1600]
    u16* W1T  = (u16*)(ws + off); off += 1048576UL;    // [E][512][256]
    u16* W2T  = (u16*)(ws + off); off += 1048576UL;    // [E][256][512]
    u16* W3T  = (u16*)(ws + off); off += 524288UL;     // [E][256][256]
    u16* XBF  = (u16*)(ws + off); off += 8388608UL;    // x bf16 [B][256]
    float* WR = (float*)(ws + off); off += 262144UL;   // gate weights [B][4]
    u16* H1   = (u16*)(ws + off); off += 67108864UL;   // [E][B][512]
    u16* H2   = (u16*)(ws + off); off += 33554432UL;   // [E][B][256]
    if (ws_size < off) return;

    int prep_blocks = (PREP_ITEMS + 255) / 256;
    prep_kernel<<<prep_blocks, 256, 0, stream>>>(Wf, W1, W2, W3, WFT, W1T, W2T, W3T, lbacc);
    fusion_kernel<<<512, 512, 0, stream>>>(vis, lang, state, WFT, bf_, gf, bfln, Wg,
                                           XBF, WR, lbacc);
    expert_gemm_kernel<<<dim3(256, 2, 4), 256, 0, stream>>>(
        XBF, 256, 0, W1T, 131072, b1, 512, H1, 512, 8388608UL);
    expert_gemm_kernel<<<dim3(256, 1, 4), 256, 0, stream>>>(
        H1, 512, 8388608UL, W2T, 131072, b2, 256, H2, 256, 4194304UL);
    combine_kernel<<<512, 512, 0, stream>>>(H2, W3T, b3, eg, eb, XBF, WR, lbacc, outp);
}

// Round 5
// 319.104 us; speedup vs baseline: 1.1151x; 1.0603x over previous
//
#include <hip/hip_runtime.h>
#include <math.h>

// ---------------------------------------------------------------------------
// FusionMoE R7: staged-bytes attack. Evidence R2/R4/R5/R6: fusion dur is
// invariant (72us) across serial/pipelined/2x-occupancy schedules -> app is
// staging-throughput-bound (~7 TB/s aggregate LDS-DMA); dur ~ staged bytes.
// Fix = arithmetic intensity: fusion M 32->64 (B staged once per 64 rows),
// expert GEMMs M 64->128. combine reverted verbatim to measured-best R2 form.
// Math identical to R2.
// ---------------------------------------------------------------------------

typedef unsigned short u16;
typedef unsigned int u32;
typedef __attribute__((ext_vector_type(8))) short bf16x8;
typedef __attribute__((ext_vector_type(4))) float f32x4;

__device__ __forceinline__ float bf2f(u16 u) {
    union { u32 i; float f; } v; v.i = ((u32)u) << 16; return v.f;
}
__device__ __forceinline__ u16 f2bf(float f) {  // RNE
    union { float f; u32 i; } v; v.f = f;
    u32 x = v.i;
    return (u16)((x + 0x7fffu + ((x >> 16) & 1u)) >> 16);
}
__device__ __forceinline__ float gelu_exact(float v) {
    return 0.5f * v * (1.0f + erff(v * 0.70710678118654752f));
}

typedef __attribute__((address_space(1))) void GV;
typedef __attribute__((address_space(3))) void SV;
__device__ __forceinline__ void gldlds(const void* g, void* l) {
    __builtin_amdgcn_global_load_lds((GV*)g, (SV*)l, 16, 0, 0);
}

// pack two f32 (bit-truncate) into one u32 of two bf16 (f0 low, f1 high)
__device__ __forceinline__ u32 pk2(u32 f0, u32 f1) {
    return __builtin_amdgcn_perm(f1, f0, 0x07060302);
}

// ----- staging helpers (XOR-8 swizzle), verified in R1 -----
// 256-thread variants (combine)
__device__ __forceinline__ void stageA64_R32(const u16* Ag, int lda, u16* As, int tid) {
    int s = tid;                        // 256 slots (32 rows x 8 chunks)
    int m = s >> 3, c = s & 7;
    gldlds(Ag + m * lda + (c ^ (m & 7)) * 8, As + s * 8);
}
__device__ __forceinline__ void stageB64(const u16* Bg, int ldb, u16* Bs, int tid) {
#pragma unroll
    for (int i = 0; i < 8; ++i) {
        int s = i * 256 + tid;          // 2048 slots (256 n-rows x 8 chunks)
        int n = s >> 3, c = s & 7;
        gldlds(Bg + n * ldb + (c ^ (n & 7)) * 8, Bs + s * 8);
    }
}
__device__ __forceinline__ void compute64_R32(const u16* As, const u16* Bs, f32x4 acc[2][4],
                                              int w, int l16, int quad) {
#pragma unroll
    for (int ks = 0; ks < 2; ++ks) {
        bf16x8 a[2];
#pragma unroll
        for (int mt = 0; mt < 2; ++mt) {
            int m = mt * 16 + l16;
            a[mt] = *(const bf16x8*)(As + m * 64 + (((ks * 4 + quad) ^ (m & 7)) << 3));
        }
#pragma unroll
        for (int nt = 0; nt < 4; ++nt) {
            int n = w * 64 + nt * 16 + l16;
            bf16x8 b = *(const bf16x8*)(Bs + n * 64 + (((ks * 4 + quad) ^ (n & 7)) << 3));
#pragma unroll
            for (int mt = 0; mt < 2; ++mt)
                acc[mt][nt] = __builtin_amdgcn_mfma_f32_16x16x32_bf16(a[mt], b, acc[mt][nt], 0, 0, 0);
        }
    }
}
// 512-thread variants (fusion / expert)
__device__ __forceinline__ void stageA128_512(const u16* Ag, int lda, u16* As, int tid) {
#pragma unroll
    for (int i = 0; i < 2; ++i) {
        int s = i * 512 + tid;          // 1024 slots (128 rows x 8 chunks)
        int m = s >> 3, c = s & 7;
        gldlds(Ag + m * lda + (c ^ (m & 7)) * 8, As + s * 8);
    }
}
__device__ __forceinline__ void stageB64_512(const u16* Bg, int ldb, u16* Bs, int tid) {
#pragma unroll
    for (int i = 0; i < 4; ++i) {
        int s = i * 512 + tid;          // 2048 slots (256 n-rows x 8 chunks)
        int n = s >> 3, c = s & 7;
        gldlds(Bg + n * ldb + (c ^ (n & 7)) * 8, Bs + s * 8);
    }
}
// 8-wave (2x4) 128-row compute (expert): wave (wrw,wc) owns 64x64
__device__ __forceinline__ void compute128_8w(const u16* As, const u16* Bs, f32x4 acc[4][4],
                                              int wrw, int wc, int l16, int quad) {
#pragma unroll
    for (int ks = 0; ks < 2; ++ks) {
        bf16x8 a[4];
#pragma unroll
        for (int mt = 0; mt < 4; ++mt) {
            int m = wrw * 64 + mt * 16 + l16;
            a[mt] = *(const bf16x8*)(As + m * 64 + (((ks * 4 + quad) ^ (m & 7)) << 3));
        }
#pragma unroll
        for (int nt = 0; nt < 4; ++nt) {
            int n = wc * 64 + nt * 16 + l16;
            bf16x8 b = *(const bf16x8*)(Bs + n * 64 + (((ks * 4 + quad) ^ (n & 7)) << 3));
#pragma unroll
            for (int mt = 0; mt < 4; ++mt)
                acc[mt][nt] = __builtin_amdgcn_mfma_f32_16x16x32_bf16(a[mt], b, acc[mt][nt], 0, 0, 0);
        }
    }
}

// ---------------------------------------------------------------------------
// K0: prep — weight transposes to bf16 + lbacc zero (weights only, ~7 MB)
// ---------------------------------------------------------------------------
#define SEG_WF  409600
#define SEG_W1  524288
#define SEG_W2  524288
#define SEG_W3  262144
#define PREP_ITEMS (SEG_WF + SEG_W1 + SEG_W2 + SEG_W3 + 8)

__global__ __launch_bounds__(256) void prep_kernel(
    const float* __restrict__ Wf, const float* __restrict__ W1, const float* __restrict__ W2,
    const float* __restrict__ W3,
    u16* __restrict__ wft, u16* __restrict__ w1t, u16* __restrict__ w2t, u16* __restrict__ w3t,
    float* __restrict__ lbacc) {
    int idx = blockIdx.x * 256 + threadIdx.x;
    if (idx < SEG_WF) {  // WfT[n<256][k<1600] = Wf[k][n]
        int n = idx / 1600, k = idx % 1600;
        wft[idx] = f2bf(Wf[(size_t)k * 256 + n]);
        return;
    }
    idx -= SEG_WF;
    if (idx < SEG_W1) {  // W1T[e][n<512][k<256] = W1[e][k][n]
        int e = idx >> 17, r = idx & 131071;
        int n = r >> 8, k = r & 255;
        w1t[idx] = f2bf(W1[(size_t)e * 131072 + (size_t)k * 512 + n]);
        return;
    }
    idx -= SEG_W1;
    if (idx < SEG_W2) {  // W2T[e][n<256][k<512] = W2[e][k][n]
        int e = idx >> 17, r = idx & 131071;
        int n = r >> 9, k = r & 511;
        w2t[idx] = f2bf(W2[(size_t)e * 131072 + (size_t)k * 256 + n]);
        return;
    }
    idx -= SEG_W2;
    if (idx < SEG_W3) {  // W3T[e][n<256][k<256] = W3[e][k][n]
        int e = idx >> 16, r = idx & 65535;
        int n = r >> 8, k = r & 255;
        w3t[idx] = f2bf(W3[(size_t)e * 65536 + (size_t)k * 256 + n]);
        return;
    }
    idx -= SEG_W3;
    if (idx < 8) lbacc[idx] = 0.0f;
}

// ---------------------------------------------------------------------------
// K1: fusion — 512 threads (8 waves as 2x4), 64x256 tile, grid 256.
// fp32 A direct (XOR-16), bf16 B. B staged once per kit for 64 rows.
// Epilogue: bias+LN+GELU -> xbf, fused gate -> wr + lb atomics.
// ---------------------------------------------------------------------------
__global__ __launch_bounds__(512, 4) void fusion_kernel(
    const float* __restrict__ vis, const float* __restrict__ lang, const float* __restrict__ state,
    const u16* __restrict__ BT, const float* __restrict__ bfv_, const float* __restrict__ gf,
    const float* __restrict__ bfln, const float* __restrict__ Wg,
    u16* __restrict__ xbf, float* __restrict__ wr, float* __restrict__ lbacc) {
    __shared__ __align__(16) u32 Af[4096];   // 16KB: 64 rows x 16 f32-chunks (XOR-16)
    __shared__ __align__(16) u16 Bs[16384];  // 32KB: 256 n x 64 k bf16
    int tid = threadIdx.x;
    int w = tid >> 6, lane = tid & 63, quad = lane >> 4, l16 = lane & 15;
    int wrw = w >> 2, wc = w & 3;            // wave = (row-half, col-quarter)
    int m0 = blockIdx.x * 64;
    f32x4 acc[2][4] = {};

    for (int kit = 0; kit < 25; ++kit) {
        const float* base; int ld;
        if (kit < 12)      { base = vis   + (size_t)m0 * 768 + kit * 64;        ld = 768; }
        else if (kit < 24) { base = lang  + (size_t)m0 * 768 + (kit - 12) * 64; ld = 768; }
        else               { base = state + (size_t)m0 * 64;                    ld = 64; }
#pragma unroll
        for (int i = 0; i < 2; ++i) {        // A: 1024 slots of 16B (4 f32)
            int s = i * 512 + tid;
            int m = s >> 4, c = s & 15;
            gldlds(base + m * ld + (c ^ (m & 15)) * 4, Af + s * 4);
        }
        stageB64_512(BT + kit * 64, 1600, Bs, tid);   // 4 loads/thread
        __syncthreads();
#pragma unroll
        for (int ks = 0; ks < 2; ++ks) {
            bf16x8 a[2];
#pragma unroll
            for (int mt = 0; mt < 2; ++mt) {
                int m = wrw * 32 + mt * 16 + l16;
                int c0 = ks * 8 + quad * 2;
                const u32* rowp = Af + m * 64;
                uint4 f0 = *(const uint4*)(rowp + (c0 ^ (m & 15)) * 4);
                uint4 f1 = *(const uint4*)(rowp + ((c0 + 1) ^ (m & 15)) * 4);
                union { u32 u[4]; bf16x8 v; } pk;
                pk.u[0] = pk2(f0.x, f0.y); pk.u[1] = pk2(f0.z, f0.w);
                pk.u[2] = pk2(f1.x, f1.y); pk.u[3] = pk2(f1.z, f1.w);
                a[mt] = pk.v;
            }
#pragma unroll
            for (int nt = 0; nt < 4; ++nt) {
                int n = wc * 64 + nt * 16 + l16;
                bf16x8 b = *(const bf16x8*)(Bs + n * 64 + (((ks * 4 + quad) ^ (n & 7)) << 3));
#pragma unroll
                for (int mt = 0; mt < 2; ++mt)
                    acc[mt][nt] = __builtin_amdgcn_mfma_f32_16x16x32_bf16(a[mt], b, acc[mt][nt], 0, 0, 0);
            }
        }
        __syncthreads();
    }

    // ---- epilogue: bias, LN, GELU, xbf store, fused gate (64 rows) ----
    float2* red  = (float2*)Af;            // 256 f2: [w][rl2]        Af[0..511]
    float*  muv  = (float*)(Af + 512);     // 64
    float*  rsv  = (float*)(Af + 576);     // 64
    float*  gred = (float*)(Af + 640);     // 1024: [w][rl2][e]       Af[640..1663]
    float*  sacc = (float*)(Af + 1664);    // 8

    float bv[4], gvv[4], blv[4]; float4 wgv[4];
#pragma unroll
    for (int nt = 0; nt < 4; ++nt) {
        int col = wc * 64 + nt * 16 + l16;
        bv[nt] = bfv_[col]; gvv[nt] = gf[col]; blv[nt] = bfln[col];
        wgv[nt] = *(const float4*)(Wg + col * 4);
    }
    if (tid < 8) sacc[tid] = 0.f;
#pragma unroll
    for (int mt = 0; mt < 2; ++mt)
#pragma unroll
        for (int r = 0; r < 4; ++r) {
            float ss = 0.f, qq = 0.f;
#pragma unroll
            for (int nt = 0; nt < 4; ++nt) {
                float v = acc[mt][nt][r] + bv[nt];
                acc[mt][nt][r] = v;
                ss += v; qq += v * v;
            }
#pragma unroll
            for (int d = 1; d < 16; d <<= 1) { ss += __shfl_xor(ss, d); qq += __shfl_xor(qq, d); }
            if (l16 == 0) red[w * 32 + mt * 16 + quad * 4 + r] = make_float2(ss, qq);
        }
    __syncthreads();
    if (tid < 64) {
        int wrh = tid >> 5, rl2 = tid & 31;
        float ss = 0.f, qq = 0.f;
#pragma unroll
        for (int ww = 0; ww < 4; ++ww) {
            float2 t = red[(wrh * 4 + ww) * 32 + rl2]; ss += t.x; qq += t.y;
        }
        float mu = ss * (1.f / 256.f);
        float var = qq * (1.f / 256.f) - mu * mu;
        muv[tid] = mu;
        rsv[tid] = 1.f / sqrtf(var + 1e-5f);
    }
    __syncthreads();
#pragma unroll
    for (int mt = 0; mt < 2; ++mt)
#pragma unroll
        for (int r = 0; r < 4; ++r) {
            int rl2 = mt * 16 + quad * 4 + r;
            int row = wrw * 32 + rl2;
            float mu = muv[row], rs = rsv[row];
#pragma unroll
            for (int nt = 0; nt < 4; ++nt) {
                int col = wc * 64 + nt * 16 + l16;
                float t = (acc[mt][nt][r] - mu) * rs * gvv[nt] + blv[nt];
                float g = gelu_exact(t);
                acc[mt][nt][r] = g;
                xbf[(size_t)(m0 + row) * 256 + col] = f2bf(g);
            }
        }
    // gate partials (fp32 x, pre-bf16-truncation)
#pragma unroll
    for (int mt = 0; mt < 2; ++mt)
#pragma unroll
        for (int r = 0; r < 4; ++r) {
            int rl2 = mt * 16 + quad * 4 + r;
            float p0 = 0.f, p1 = 0.f, p2 = 0.f, p3 = 0.f;
#pragma unroll
            for (int nt = 0; nt < 4; ++nt) {
                float g = acc[mt][nt][r];
                p0 += g * wgv[nt].x; p1 += g * wgv[nt].y;
                p2 += g * wgv[nt].z; p3 += g * wgv[nt].w;
            }
#pragma unroll
            for (int d = 1; d < 16; d <<= 1) {
                p0 += __shfl_xor(p0, d); p1 += __shfl_xor(p1, d);
                p2 += __shfl_xor(p2, d); p3 += __shfl_xor(p3, d);
            }
            if (l16 == 0) {
                float* gp = gred + w * 128 + rl2 * 4;
                gp[0] = p0; gp[1] = p1; gp[2] = p2; gp[3] = p3;
            }
        }
    __syncthreads();
    if (tid < 64) {
        int row = tid, wrh = row >> 5, rl2 = row & 31;
        float lg[4];
#pragma unroll
        for (int e = 0; e < 4; ++e) {
            float s = 0.f;
#pragma unroll
            for (int ww = 0; ww < 4; ++ww) s += gred[(wrh * 4 + ww) * 128 + rl2 * 4 + e];
            lg[e] = s;
        }
        float mx = fmaxf(fmaxf(lg[0], lg[1]), fmaxf(lg[2], lg[3]));
        float ex[4]; float Z = 0.f;
#pragma unroll
        for (int e = 0; e < 4; ++e) { ex[e] = expf(lg[e] - mx); Z += ex[e]; }
        int i0 = 0; float v0 = lg[0];
#pragma unroll
        for (int e = 1; e < 4; ++e) if (lg[e] > v0) { v0 = lg[e]; i0 = e; }
        int i1 = -1; float v1 = -1e30f;
#pragma unroll
        for (int e = 0; e < 4; ++e) if (e != i0 && lg[e] > v1) { v1 = lg[e]; i1 = e; }
        float t = expf(v1 - v0);
        float wA = 1.f / (1.f + t), wB = t / (1.f + t);
        float w4[4] = {0.f, 0.f, 0.f, 0.f};
        w4[i0] = wA; w4[i1] = wB;
#pragma unroll
        for (int e = 0; e < 4; ++e) wr[(size_t)(m0 + row) * 4 + e] = w4[e];
#pragma unroll
        for (int e = 0; e < 4; ++e) atomicAdd(&sacc[e], ex[e] / Z);
        atomicAdd(&sacc[4 + i0], 1.f);
        atomicAdd(&sacc[4 + i1], 1.f);
    }
    __syncthreads();
    if (tid < 8) atomicAdd(lbacc + tid, sacc[tid]);
}

// ---------------------------------------------------------------------------
// K2: expert GEMM + bias + GELU, batched over blockIdx.z = expert.
// 512 threads (8 waves as 2x4), 128x256 tile: B staged once per 128 rows.
// ---------------------------------------------------------------------------
__global__ __launch_bounds__(512, 4) void expert_gemm_kernel(
    const u16* __restrict__ A, int lda, size_t aE,
    const u16* __restrict__ BT, size_t bE,
    const float* __restrict__ bias, int biasE,
    u16* __restrict__ outp, int ldo, size_t oE) {
    __shared__ __align__(16) u16 As[8192];       // 16KB: 128 rows x 64 k
    __shared__ __align__(16) u16 Bs[16384];      // 32KB: 256 n x 64 k
    int tid = threadIdx.x;
    int w = tid >> 6, lane = tid & 63, quad = lane >> 4, l16 = lane & 15;
    int wrw = w >> 2, wc = w & 3;
    int m0 = blockIdx.x * 128;
    int col0 = blockIdx.y * 256;
    int e = blockIdx.z;
    f32x4 acc[4][4] = {};
    const u16* Ag = A + e * aE + (size_t)m0 * lda;
    const u16* Bg = BT + e * bE + (size_t)col0 * lda;
    int kiters = lda >> 6;
    for (int kit = 0; kit < kiters; ++kit) {
        stageA128_512(Ag + kit * 64, lda, As, tid);
        stageB64_512(Bg + kit * 64, lda, Bs, tid);
        __syncthreads();
        compute128_8w(As, Bs, acc, wrw, wc, l16, quad);
        __syncthreads();
    }
#pragma unroll
    for (int nt = 0; nt < 4; ++nt) {
        int col = col0 + wc * 64 + nt * 16 + l16;
        float bvv = bias[e * biasE + col];
#pragma unroll
        for (int mt = 0; mt < 4; ++mt)
#pragma unroll
            for (int r = 0; r < 4; ++r) {
                int row = m0 + wrw * 64 + mt * 16 + quad * 4 + r;
                outp[e * oE + (size_t)row * ldo + col] = f2bf(gelu_exact(acc[mt][nt][r] + bvv));
            }
    }
}

// ---------------------------------------------------------------------------
// K3: combine — verbatim R2 form (measured best): 256t, 32-row tiles,
// single-buffer, xs in LDS. h2@W3 + b3 + x -> LN -> *eg+eb, out += w*y.
// ---------------------------------------------------------------------------
__global__ __launch_bounds__(256) void combine_kernel(
    const u16* __restrict__ h2, const u16* __restrict__ W3T,
    const float* __restrict__ b3, const float* __restrict__ eg, const float* __restrict__ eb,
    const u16* __restrict__ xbf, const float* __restrict__ wr,
    const float* __restrict__ lbacc, float* __restrict__ outp) {
    __shared__ __align__(16) u16 As[2048];    // 4KB: 32 rows x 64 k
    __shared__ __align__(16) u16 Bs[16384];   // 32KB
    __shared__ __align__(16) u16 xs[8192];    // 16KB: 32 rows x 256 bf16
    __shared__ float wl[128];
    int tid = threadIdx.x;
    int w = tid >> 6, lane = tid & 63, quad = lane >> 4, l16 = lane & 15;
    int m0 = blockIdx.x * 32;
    if (blockIdx.x == 0 && tid == 0) {        // lb_loss (lbacc complete: fusion done)
        float lb = 0.f;
#pragma unroll
        for (int e = 0; e < 4; ++e)
            lb += (lbacc[4 + e] / 32768.f) * (lbacc[e] / 16384.f);
        outp[4194304] = 4.f * lb;
    }
#pragma unroll
    for (int i = 0; i < 4; ++i) {
        int s = i * 256 + tid;
        *(uint4*)(xs + s * 8) = *(const uint4*)(xbf + (size_t)m0 * 256 + s * 8);
    }
    if (tid < 128) wl[tid] = wr[(size_t)m0 * 4 + tid];
    float2* red = (float2*)As;               // alias (barrier-guarded)
    float* muv = (float*)((char*)As + 1024);
    float* rsv = (float*)((char*)As + 1152);
    f32x4 oacc[2][4] = {};
    for (int e = 0; e < 4; ++e) {
        __syncthreads();                     // covers xs/wl (e=0), red reuse (e>0)
        f32x4 acc[2][4] = {};
        const u16* Ag = h2 + ((size_t)e * 16384 + m0) * 256;
        const u16* Bg = W3T + (size_t)e * 65536;
        for (int kit = 0; kit < 4; ++kit) {
            stageA64_R32(Ag + kit * 64, 256, As, tid);
            stageB64(Bg + kit * 64, 256, Bs, tid);
            __syncthreads();
            compute64_R32(As, Bs, acc, w, l16, quad);
            __syncthreads();
        }
        float b3v[4], egv[4], ebv[4];
#pragma unroll
        for (int nt = 0; nt < 4; ++nt) {
            int col = w * 64 + nt * 16 + l16;
            b3v[nt] = b3[e * 256 + col]; egv[nt] = eg[e * 256 + col]; ebv[nt] = eb[e * 256 + col];
        }
#pragma unroll
        for (int mt = 0; mt < 2; ++mt)
#pragma unroll
            for (int r = 0; r < 4; ++r) {
                int rl = mt * 16 + quad * 4 + r;
                float ss = 0.f, qq = 0.f;
#pragma unroll
                for (int nt = 0; nt < 4; ++nt) {
                    int col = w * 64 + nt * 16 + l16;
                    float v = acc[mt][nt][r] + b3v[nt] + bf2f(xs[rl * 256 + col]);
                    acc[mt][nt][r] = v;
                    ss += v; qq += v * v;
                }
#pragma unroll
                for (int d = 1; d < 16; d <<= 1) { ss += __shfl_xor(ss, d); qq += __shfl_xor(qq, d); }
                if (l16 == 0) red[w * 32 + rl] = make_float2(ss, qq);
            }
        __syncthreads();
        if (tid < 32) {
            float ss = 0.f, qq = 0.f;
#pragma unroll
            for (int ww = 0; ww < 4; ++ww) { float2 t = red[ww * 32 + tid]; ss += t.x; qq += t.y; }
            float mu = ss * (1.f / 256.f);
            float var = qq * (1.f / 256.f) - mu * mu;
            muv[tid] = mu;
            rsv[tid] = 1.f / sqrtf(var + 1e-5f);
        }
        __syncthreads();
#pragma unroll
        for (int mt = 0; mt < 2; ++mt)
#pragma unroll
            for (int r = 0; r < 4; ++r) {
                int rl = mt * 16 + quad * 4 + r;
                float mu = muv[rl], rs = rsv[rl], we = wl[rl * 4 + e];
#pragma unroll
                for (int nt = 0; nt < 4; ++nt) {
                    float y = (acc[mt][nt][r] - mu) * rs * egv[nt] + ebv[nt];
                    oacc[mt][nt][r] += we * y;
                }
            }
    }
#pragma unroll
    for (int mt = 0; mt < 2; ++mt)
#pragma unroll
        for (int r = 0; r < 4; ++r) {
            int rl = mt * 16 + quad * 4 + r;
#pragma unroll
            for (int nt = 0; nt < 4; ++nt) {
                int col = w * 64 + nt * 16 + l16;
                outp[(size_t)(m0 + rl) * 256 + col] = oacc[mt][nt][r];
            }
        }
}

// ---------------------------------------------------------------------------
extern "C" void kernel_launch(void* const* d_in, const int* in_sizes, int n_in,
                              void* d_out, int out_size, void* d_ws, size_t ws_size,
                              hipStream_t stream) {
    const float* vis   = (const float*)d_in[0];
    const float* lang  = (const float*)d_in[1];
    const float* state = (const float*)d_in[2];
    const float* Wf    = (const float*)d_in[3];
    const float* bf_   = (const float*)d_in[4];
    const float* gf    = (const float*)d_in[5];
    const float* bfln  = (const float*)d_in[6];
    const float* Wg    = (const float*)d_in[7];
    const float* W1    = (const float*)d_in[8];
    const float* b1    = (const float*)d_in[9];
    const float* W2    = (const float*)d_in[10];
    const float* b2    = (const float*)d_in[11];
    const float* W3    = (const float*)d_in[12];
    const float* b3    = (const float*)d_in[13];
    const float* eg    = (const float*)d_in[14];
    const float* eb    = (const float*)d_in[15];
    float* outp = (float*)d_out;

    char* ws = (char*)d_ws;
    size_t off = 0;
    float* lbacc = (float*)(ws + off); off += 256;
    u16* WFT  = (u16*)(ws + off); off += 819200UL;     // WfT [256][1600]
    u16* W1T  = (u16*)(ws + off); off += 1048576UL;    // [E][512][256]
    u16* W2T  = (u16*)(ws + off); off += 1048576UL;    // [E][256][512]
    u16* W3T  = (u16*)(ws + off); off += 524288UL;     // [E][256][256]
    u16* XBF  = (u16*)(ws + off); off += 8388608UL;    // x bf16 [B][256]
    float* WR = (float*)(ws + off); off += 262144UL;   // gate weights [B][4]
    u16* H1   = (u16*)(ws + off); off += 67108864UL;   // [E][B][512]
    u16* H2   = (u16*)(ws + off); off += 33554432UL;   // [E][B][256]
    if (ws_size < off) return;

    int prep_blocks = (PREP_ITEMS + 255) / 256;
    prep_kernel<<<prep_blocks, 256, 0, stream>>>(Wf, W1, W2, W3, WFT, W1T, W2T, W3T, lbacc);
    fusion_kernel<<<256, 512, 0, stream>>>(vis, lang, state, WFT, bf_, gf, bfln, Wg,
                                           XBF, WR, lbacc);
    expert_gemm_kernel<<<dim3(128, 2, 4), 512, 0, stream>>>(
        XBF, 256, 0, W1T, 131072, b1, 512, H1, 512, 8388608UL);
    expert_gemm_kernel<<<dim3(128, 1, 4), 512, 0, stream>>>(
        H1, 512, 8388608UL, W2T, 131072, b2, 256, H2, 256, 4194304UL);
    combine_kernel<<<512, 256, 0, stream>>>(H2, W3T, b3, eg, eb, XBF, WR, lbacc, outp);
}